// Round 8
// baseline (247.550 us; speedup 1.0000x reference)
//
#include <hip/hip_runtime.h>
#include <math.h>

// Problem constants
#define BATCH   2
#define LSEQ    1024
#define DMODEL  1024
#define DI      2048      // D_INNER
#define NSTATE  16
#define DTR     64        // DT_RANK
#define SSMP    128       // padded ssm width (96 -> 128); B at +64, C at +80
#define MROWS   2048      // BATCH*LSEQ
#define CHUNK   32
#define NCHUNK  32        // LSEQ / CHUNK

typedef unsigned short u16;
typedef __attribute__((ext_vector_type(8))) short short8;   // 8 bf16 (4 VGPRs)
typedef __attribute__((ext_vector_type(4))) float f32x4;

__device__ __forceinline__ float silu_f(float x) {
  return x / (1.f + __expf(-x));
}
__device__ __forceinline__ float softplus_f(float x) {
  // fast form: max(x,0) + log(1 + exp(-|x|)); |arg of log| in [1,2] -> safe
  return fmaxf(x, 0.f) + __logf(1.f + __expf(-fabsf(x)));
}
__device__ __forceinline__ u16 f2bf(float f) {   // RNE
  unsigned u = __float_as_uint(f);
  return (u16)((u + 0x7fffu + ((u >> 16) & 1u)) >> 16);
}
__device__ __forceinline__ float bf2f(u16 v) {
  return __uint_as_float(((unsigned)v) << 16);
}

// async global -> LDS, 16 B per lane; LDS dest = wave-uniform base + lane*16
__device__ __forceinline__ void gload_lds16(const u16* g, u16* l) {
  __builtin_amdgcn_global_load_lds(
      (const __attribute__((address_space(1))) unsigned int*)(const void*)g,
      (__attribute__((address_space(3))) unsigned int*)(void*)l, 16, 0, 0);
}

// ---------------------------------------------------------------------------
// Fused preprocessing: one kernel, block-range dispatch.
//   [0,2048)        : cvt x fp32->bf16 (2M elems, x4 vec)
//   [2048,4096)     : transpose W_in   [1024][2048] -> WinT  [2048][1024]
//   [4096,4288)     : transpose W_x    [2048][96]   -> WxT   [96 of 128][2048]
//   [4288,4352)     : zero WxT rows 96..127
//   [4352,6400)     : transpose W_out  [2048][1024] -> WoutT [1024][2048]
// (W_dt is used in fp32 directly by delta_kernel -- no transpose needed.)
// ---------------------------------------------------------------------------
__device__ __forceinline__ void transpose_dev(
    float (*t)[33], const float* __restrict__ in, u16* __restrict__ out,
    int R, int C, int bx, int by, int tid)
{
  const int tx = tid & 31, ty = tid >> 5;          // 32 x 8
  const int c0 = bx * 32, r0 = by * 32;
#pragma unroll
  for (int k = 0; k < 4; ++k)
    t[ty + 8 * k][tx] = in[(size_t)(r0 + ty + 8 * k) * C + c0 + tx];
  __syncthreads();
#pragma unroll
  for (int k = 0; k < 4; ++k)
    out[(size_t)(c0 + ty + 8 * k) * R + r0 + tx] = f2bf(t[tx][ty + 8 * k]);
}

__global__ __launch_bounds__(256) void prep_kernel(
    const float* __restrict__ x, const float* __restrict__ W_in,
    const float* __restrict__ W_x, const float* __restrict__ W_out,
    u16* __restrict__ x_bf, u16* __restrict__ WinT, u16* __restrict__ WxT,
    u16* __restrict__ WoutT)
{
  __shared__ float ts[32][33];
  const int tid = threadIdx.x;
  int bi = blockIdx.x;
  if (bi < 2048) {                      // cvt x
    const int i = (bi * 256 + tid) * 4;
    float4 v = *(const float4*)(x + i);
    ushort4 o;
    o.x = f2bf(v.x); o.y = f2bf(v.y); o.z = f2bf(v.z); o.w = f2bf(v.w);
    *(ushort4*)(x_bf + i) = o;
    return;
  }
  bi -= 2048;
  if (bi < 2048) {                      // W_in: grid (64, 32)
    transpose_dev(ts, W_in, WinT, 1024, 2048, bi & 63, bi >> 6, tid);
    return;
  }
  bi -= 2048;
  if (bi < 192) {                       // W_x: grid (3, 64)
    transpose_dev(ts, W_x, WxT, 2048, 96, bi % 3, bi / 3, tid);
    return;
  }
  bi -= 192;
  if (bi < 64) {                        // zero WxT rows 96..127 (64K u16)
    const int i = (bi * 256 + tid) * 4;
    *(ushort4*)(WxT + 96 * 2048 + i) = make_ushort4(0, 0, 0, 0);
    return;
  }
  bi -= 64;
  {                                     // W_out: grid (32, 64)
    transpose_dev(ts, W_out, WoutT, 2048, 1024, bi & 31, bi >> 5, tid);
  }
}

// ---------------------------------------------------------------------------
// bf16 MFMA GEMM, m97-style: C[M x TNxgrid] = A[M x K] * Bt[N x K]^T
// Tile 128(M) x TN(N), BK=32, 256 threads = 4 waves.
//   TN==128: waves 2x2, each 64x64 (4x4 frags)
//   TN==64 : waves 4x1 on M, each 32x64 (2x4 frags)
// Staging: global_load_lds dwordx4 with store-side XOR chunk swizzle.
// SPLITK>1: deterministic partials at C + z*(gridDim.y*128*ldc).
// OBF==1: output bf16 (u16) instead of fp32.
// ---------------------------------------------------------------------------
template<int SPLITK, int TN, int OBF>
__global__ __launch_bounds__(256) void mgemm(
    const u16* __restrict__ A, int lda,
    const u16* __restrict__ Bt, int ldb,
    void* __restrict__ Cv, int ldc, int K)
{
  constexpr int WI = (TN == 128) ? 4 : 2;   // a-frags per wave
  __shared__ u16 Al[128 * 32];
  __shared__ u16 Bl[TN * 32];
  const int tid = threadIdx.x;
  const int bm = blockIdx.y * 128;
  const int bn = blockIdx.x * TN;
  const int lane = tid & 63;
  const int w = tid >> 6;
  const int wm = (TN == 128) ? (w & 1) * 64 : w * 32;
  const int wn = (TN == 128) ? (w >> 1) * 64 : 0;
  const int quad = lane >> 4;
  const int lm = lane & 15;

  const int Kper = K / SPLITK;
  const int k_beg = blockIdx.z * Kper;

  const int clog8 = (((lane & 3) ^ ((lane >> 3) & 3)) << 3);  // u16 offset
  const int rA = w * 32 + (lane >> 2);
  const int rB = ((TN == 128) ? w * 32 : w * 16) + (lane >> 2);
  const u16* gA0 = A + (size_t)(bm + rA) * lda + k_beg + clog8;
  const u16* gA1 = gA0 + (size_t)16 * lda;
  const u16* gB0 = Bt + (size_t)(bn + rB) * ldb + k_beg + clog8;
  const u16* gB1 = gB0 + (size_t)16 * ldb;
  u16* lA0 = &Al[(w * 32) * 32];
  u16* lA1 = &Al[(w * 32 + 16) * 32];
  u16* lB0 = &Bl[(((TN == 128) ? w * 32 : w * 16)) * 32];
  u16* lB1 = &Bl[((TN == 128) ? (w * 32 + 16) : 0) * 32];

  const int cph8 = ((quad ^ ((lm >> 1) & 3)) << 3);

  f32x4 acc[WI][4] = {};

  for (int ks = 0; ks < Kper; ks += 32) {
    gload_lds16(gA0, lA0);
    gload_lds16(gA1, lA1);
    gload_lds16(gB0, lB0);
    if (TN == 128) gload_lds16(gB1, lB1);
    gA0 += 32; gA1 += 32; gB0 += 32; gB1 += 32;
    __syncthreads();

    short8 a[WI], b[4];
#pragma unroll
    for (int i = 0; i < WI; ++i)
      a[i] = *(const short8*)&Al[(wm + i * 16 + lm) * 32 + cph8];
#pragma unroll
    for (int j = 0; j < 4; ++j)
      b[j] = *(const short8*)&Bl[(wn + j * 16 + lm) * 32 + cph8];
#pragma unroll
    for (int i = 0; i < WI; ++i)
#pragma unroll
      for (int j = 0; j < 4; ++j)
        acc[i][j] = __builtin_amdgcn_mfma_f32_16x16x32_bf16(a[i], b[j], acc[i][j], 0, 0, 0);
    __syncthreads();
  }

#pragma unroll
  for (int i = 0; i < WI; ++i) {
#pragma unroll
    for (int r = 0; r < 4; ++r) {
      const int row = bm + wm + i * 16 + quad * 4 + r;
#pragma unroll
      for (int j = 0; j < 4; ++j) {
        const int col = bn + wn + j * 16 + lm;
        float v = acc[i][j][r];
        if (OBF) {
          ((u16*)Cv)[(size_t)row * ldc + col] = f2bf(v);
        } else {
          float* Cz = (float*)Cv;
          if (SPLITK > 1) Cz += (size_t)blockIdx.z * gridDim.y * 128 * ldc;
          Cz[(size_t)row * ldc + col] = v;
        }
      }
    }
  }
}

// ---------------------------------------------------------------------------
// Reduce gemm3's 8 split-K partials -> SSMB fp32.
// ---------------------------------------------------------------------------
__global__ __launch_bounds__(256) void reduce3(
    const float* __restrict__ P3, float* __restrict__ SSMB)
{
  const int t = blockIdx.x * 256 + threadIdx.x;   // over 2048*128
  float s = 0.f;
#pragma unroll
  for (int z = 0; z < 8; ++z) s += P3[(size_t)z * (MROWS * SSMP) + t];
  SSMB[t] = s;
}

// ---------------------------------------------------------------------------
// DELTA = softplus(SSMB[:, :64] @ W_dt + b_dt), fp32 out.
// Block = 8 rows x 2048 cols (grid 256); thread = 8 rows x 8 cols.
// dt rows broadcast from LDS; W_dt streamed fp32 row-wise (coalesced 2KB/wave).
// ---------------------------------------------------------------------------
__global__ __launch_bounds__(256) void delta_kernel(
    const float* __restrict__ SSMB, const float* __restrict__ W_dt,
    const float* __restrict__ b_dt, float* __restrict__ DELTA)
{
  __shared__ float dts[8][64];
  const int tid = threadIdx.x;
  const int r0 = blockIdx.x * 8;
  {
    const int r = tid >> 5, k = (tid & 31) * 2;   // 512 elems, 2/thread
    const float2 v = *(const float2*)&SSMB[(size_t)(r0 + r) * SSMP + k];
    dts[r][k] = v.x; dts[r][k + 1] = v.y;
  }
  __syncthreads();

  const int c0 = tid * 8;
  float acc[8][8];
  {
    float4 ba = *(const float4*)&b_dt[c0];
    float4 bb = *(const float4*)&b_dt[c0 + 4];
    const float bias[8] = {ba.x, ba.y, ba.z, ba.w, bb.x, bb.y, bb.z, bb.w};
#pragma unroll
    for (int r = 0; r < 8; ++r)
#pragma unroll
      for (int c = 0; c < 8; ++c) acc[r][c] = bias[c];
  }

  for (int k = 0; k < DTR; ++k) {
    const float4 wa = *(const float4*)&W_dt[(size_t)k * DI + c0];
    const float4 wb = *(const float4*)&W_dt[(size_t)k * DI + c0 + 4];
    const float w[8] = {wa.x, wa.y, wa.z, wa.w, wb.x, wb.y, wb.z, wb.w};
#pragma unroll
    for (int r = 0; r < 8; ++r) {
      const float d = dts[r][k];
#pragma unroll
      for (int c = 0; c < 8; ++c) acc[r][c] = fmaf(w[c], d, acc[r][c]);
    }
  }

#pragma unroll
  for (int r = 0; r < 8; ++r) {
    float4 o0, o1;
    o0.x = softplus_f(acc[r][0]); o0.y = softplus_f(acc[r][1]);
    o0.z = softplus_f(acc[r][2]); o0.w = softplus_f(acc[r][3]);
    o1.x = softplus_f(acc[r][4]); o1.y = softplus_f(acc[r][5]);
    o1.z = softplus_f(acc[r][6]); o1.w = softplus_f(acc[r][7]);
    float* op = &DELTA[(size_t)(r0 + r) * DI + c0];
    *(float4*)op = o0;
    *(float4*)(op + 4) = o1;
  }
}

// ---------------------------------------------------------------------------
// Depthwise causal conv (k=4) + bias + SiLU. Reads XVb bf16, writes XSb bf16.
// ---------------------------------------------------------------------------
__global__ __launch_bounds__(256) void conv_silu_kernel(
    const u16* __restrict__ XVb, const float* __restrict__ cw,
    const float* __restrict__ cb, u16* __restrict__ XSb)
{
  const int idx = blockIdx.x * 256 + threadIdx.x;   // over B*L*DI
  const int d = idx & (DI - 1);
  const int bl = idx >> 11;
  const int l = bl & (LSEQ - 1);
  const float w0 = cw[d * 4 + 0], w1 = cw[d * 4 + 1];
  const float w2 = cw[d * 4 + 2], w3 = cw[d * 4 + 3];
  const u16* p = XVb + (size_t)idx;
  float acc = cb[d];
  acc = fmaf(w3, bf2f(p[0]), acc);
  if (l >= 1) acc = fmaf(w2, bf2f(p[-DI]), acc);
  if (l >= 2) acc = fmaf(w1, bf2f(p[-2 * DI]), acc);
  if (l >= 3) acc = fmaf(w0, bf2f(p[-3 * DI]), acc);
  XSb[idx] = f2bf(silu_f(acc));
}

// ---------------------------------------------------------------------------
// Chunked parallel scan, register-state version (one thread per (b,chunk,d)).
// ---------------------------------------------------------------------------
__global__ __launch_bounds__(256) void scan_pass1(
    const float* __restrict__ DELTA, const u16* __restrict__ XSb,
    const float* __restrict__ SSMB, const float* __restrict__ A_log,
    float* __restrict__ AGG_A, float* __restrict__ AGG_H)
{
  __shared__ float Bs[CHUNK * 16];
  const int tid = threadIdx.x;
  const int db = blockIdx.x & 7;
  const int c  = (blockIdx.x >> 3) & (NCHUNK - 1);
  const int b  = blockIdx.x >> 8;
  const int d  = db * 256 + tid;
  const int l0 = c * CHUNK;

  for (int i = tid; i < CHUNK * 16; i += 256) {
    const int l = i >> 4, n = i & 15;
    Bs[i] = SSMB[((size_t)(b * LSEQ + l0 + l)) * SSMP + DTR + n];
  }
  __syncthreads();

  float An[16];
  {
    const float* ar = A_log + d * 16;
#pragma unroll
    for (int n = 0; n < 16; ++n) An[n] = -__expf(ar[n]);
  }

  float h[16];
#pragma unroll
  for (int n = 0; n < 16; ++n) h[n] = 0.f;
  float S = 0.f;

  const float* dp = DELTA + ((size_t)(b * LSEQ + l0)) * DI + d;
  const u16*   xp = XSb   + ((size_t)(b * LSEQ + l0)) * DI + d;

  for (int l = 0; l < CHUNK; ++l) {
    const float delta = *dp; dp += DI;
    const float xv = bf2f(*xp); xp += DI;
    S += delta;
    const float dt = delta * xv;
    const f32x4 b0 = *(const f32x4*)&Bs[l * 16];
    const f32x4 b1 = *(const f32x4*)&Bs[l * 16 + 4];
    const f32x4 b2 = *(const f32x4*)&Bs[l * 16 + 8];
    const f32x4 b3 = *(const f32x4*)&Bs[l * 16 + 12];
#pragma unroll
    for (int n = 0; n < 16; ++n) {
      const float Bv = (n < 4) ? b0[n & 3] : (n < 8) ? b1[n & 3] : (n < 12) ? b2[n & 3] : b3[n & 3];
      const float dA = __expf(delta * An[n]);
      h[n] = fmaf(dA, h[n], Bv * dt);
    }
  }

  const size_t base = (((size_t)(b * NCHUNK + c) * DI + d) << 4);
  f32x4 oa[4], oh[4];
#pragma unroll
  for (int q = 0; q < 4; ++q) {
#pragma unroll
    for (int r = 0; r < 4; ++r) {
      oa[q][r] = __expf(An[q * 4 + r] * S);
      oh[q][r] = h[q * 4 + r];
    }
    *(f32x4*)&AGG_A[base + q * 4] = oa[q];
    *(f32x4*)&AGG_H[base + q * 4] = oh[q];
  }
}

// In-place prefix over chunks: AGG_H[ai] <- exclusive prefix (h_init).
__global__ __launch_bounds__(256) void scan_pass2(
    const float* __restrict__ AGG_A, float* __restrict__ AGG_H)
{
  const int t = blockIdx.x * 256 + threadIdx.x;   // over B*DI*NSTATE
  const int dn = t & (DI * NSTATE - 1);
  const int b = t >> 15;
  size_t ai = (size_t)b * NCHUNK * DI * NSTATE + dn;
  const size_t stride = (size_t)DI * NSTATE;
  float h = 0.f;
#pragma unroll
  for (int c = 0; c < NCHUNK; ++c) {
    const float a = AGG_A[ai];
    const float hp = AGG_H[ai];
    AGG_H[ai] = h;
    h = fmaf(a, h, hp);
    ai += stride;
  }
}

__global__ __launch_bounds__(256) void scan_pass3(
    const float* __restrict__ DELTA, const u16* __restrict__ XSb,
    const float* __restrict__ SSMB, const float* __restrict__ A_log,
    const float* __restrict__ Dp, const float* __restrict__ HINIT,
    u16* __restrict__ Yb)
{
  __shared__ float Bs[CHUNK * 16];
  __shared__ float Cs[CHUNK * 16];
  const int tid = threadIdx.x;
  const int db = blockIdx.x & 7;
  const int c  = (blockIdx.x >> 3) & (NCHUNK - 1);
  const int b  = blockIdx.x >> 8;
  const int d  = db * 256 + tid;
  const int l0 = c * CHUNK;

  for (int i = tid; i < CHUNK * 16; i += 256) {
    const int l = i >> 4, n = i & 15;
    const size_t row = ((size_t)(b * LSEQ + l0 + l)) * SSMP;
    Bs[i] = SSMB[row + DTR + n];
    Cs[i] = SSMB[row + DTR + NSTATE + n];
  }
  __syncthreads();

  float An[16];
  {
    const float* ar = A_log + d * 16;
#pragma unroll
    for (int n = 0; n < 16; ++n) An[n] = -__expf(ar[n]);
  }
  const float Dd = Dp[d];

  const size_t base = (((size_t)(b * NCHUNK + c) * DI + d) << 4);
  float h[16];
#pragma unroll
  for (int q = 0; q < 4; ++q) {
    const f32x4 hv = *(const f32x4*)&HINIT[base + q * 4];
#pragma unroll
    for (int r = 0; r < 4; ++r) h[q * 4 + r] = hv[r];
  }

  const float* dp = DELTA + ((size_t)(b * LSEQ + l0)) * DI + d;
  const u16*   xp = XSb   + ((size_t)(b * LSEQ + l0)) * DI + d;
  u16*         yp = Yb    + ((size_t)(b * LSEQ + l0)) * DI + d;

  for (int l = 0; l < CHUNK; ++l) {
    const float delta = *dp; dp += DI;
    const float xv = bf2f(*xp); xp += DI;
    const float dt = delta * xv;
    float y = xv * Dd;
    const f32x4 b0 = *(const f32x4*)&Bs[l * 16];
    const f32x4 b1 = *(const f32x4*)&Bs[l * 16 + 4];
    const f32x4 b2 = *(const f32x4*)&Bs[l * 16 + 8];
    const f32x4 b3 = *(const f32x4*)&Bs[l * 16 + 12];
    const f32x4 c0 = *(const f32x4*)&Cs[l * 16];
    const f32x4 c1 = *(const f32x4*)&Cs[l * 16 + 4];
    const f32x4 c2 = *(const f32x4*)&Cs[l * 16 + 8];
    const f32x4 c3 = *(const f32x4*)&Cs[l * 16 + 12];
#pragma unroll
    for (int n = 0; n < 16; ++n) {
      const float Bv = (n < 4) ? b0[n & 3] : (n < 8) ? b1[n & 3] : (n < 12) ? b2[n & 3] : b3[n & 3];
      const float Cv = (n < 4) ? c0[n & 3] : (n < 8) ? c1[n & 3] : (n < 12) ? c2[n & 3] : c3[n & 3];
      const float dA = __expf(delta * An[n]);
      h[n] = fmaf(dA, h[n], Bv * dt);
      y = fmaf(h[n], Cv, y);
    }
    *yp = f2bf(y); yp += DI;
  }
}

// ---------------------------------------------------------------------------
extern "C" void kernel_launch(void* const* d_in, const int* in_sizes, int n_in,
                              void* d_out, int out_size, void* d_ws, size_t ws_size,
                              hipStream_t stream)
{
  const float* x      = (const float*)d_in[0];
  const float* W_in   = (const float*)d_in[1];
  const float* conv_w = (const float*)d_in[2];
  const float* conv_b = (const float*)d_in[3];
  const float* W_x    = (const float*)d_in[4];
  const float* W_dt   = (const float*)d_in[5];
  const float* b_dt   = (const float*)d_in[6];
  const float* A_log  = (const float*)d_in[7];
  const float* Dp     = (const float*)d_in[8];
  const float* W_out  = (const float*)d_in[9];
  float* out = (float*)d_out;
  char* W = (char*)d_ws;

  const size_t MB = 1u << 20;
  // byte layout (46 MB), time-multiplexed:
  // [0,8)   : XVb bf16 (gemm1->conv) -> AGG_A (scan1->2) -> Yb (scan3->gemm6)
  // [8,16)  : AGG_H (scan1->3, in-place HINIT after pass2)
  // [16,32) : x_bf[16,20)+WinT[20,24) (prep->gemm1) -> P3 8MB [16,24)
  //           (gemm3->reduce3) -> DELTA 16MB [16,32) (delta->scan)
  // [32,40) : XSb bf16
  // [40,41) : SSMB fp32 [2048][128]
  // [41,45) : WoutT
  // [45,46) : WxT
  u16*   XVb   = (u16*)  (W + 0);
  float* AGG_A = (float*)(W + 0);
  u16*   Yb    = (u16*)  (W + 0);
  float* AGG_H = (float*)(W + 8 * MB);
  u16*   x_bf  = (u16*)  (W + 16 * MB);
  u16*   WinT  = (u16*)  (W + 20 * MB);
  float* P3    = (float*)(W + 16 * MB);
  float* DELTA = (float*)(W + 16 * MB);
  u16*   XSb   = (u16*)  (W + 32 * MB);
  float* SSMB  = (float*)(W + 40 * MB);
  u16*   WoutT = (u16*)  (W + 41 * MB);
  u16*   WxT   = (u16*)  (W + 45 * MB);

  dim3 blk(256);

  // 0) fused preprocessing (cvt + 3 transposes + WxT pad-zero)
  prep_kernel<<<dim3(6400), blk, 0, stream>>>(
      x, W_in, W_x, W_out, x_bf, WinT, WxT, WoutT);

  // 1) xv = x @ W_in  (M=2048 N=2048 K=1024), TN=64, bf16 out -> XVb
  mgemm<1, 64, 1><<<dim3(32, 16, 1), blk, 0, stream>>>(
      x_bf, DMODEL, WinT, DMODEL, XVb, DI, DMODEL);

  // 2) conv + silu (bf16 in) -> XSb bf16
  conv_silu_kernel<<<dim3((BATCH * LSEQ * DI) / 256), blk, 0, stream>>>(
      XVb, conv_w, conv_b, XSb);

  // 3) ssm partials (M=2048 N=128pad K=2048, TN=64 splitK=8) -> P3, reduce
  mgemm<8, 64, 0><<<dim3(2, 16, 8), blk, 0, stream>>>(
      XSb, DI, WxT, DI, P3, SSMP, DI);
  reduce3<<<dim3(MROWS * SSMP / 256), blk, 0, stream>>>(P3, SSMB);

  // 4) delta = softplus(ssm[:, :64] @ W_dt + b_dt) -> DELTA fp32 (VALU kernel)
  delta_kernel<<<dim3(MROWS / 8), blk, 0, stream>>>(SSMB, W_dt, b_dt, DELTA);

  // 5) chunked scan (register-state)
  scan_pass1<<<dim3(BATCH * NCHUNK * (DI / 256)), blk, 0, stream>>>(
      DELTA, XSb, SSMB, A_log, AGG_A, AGG_H);
  scan_pass2<<<dim3((BATCH * DI * NSTATE) / 256), blk, 0, stream>>>(
      AGG_A, AGG_H);
  scan_pass3<<<dim3(BATCH * NCHUNK * (DI / 256)), blk, 0, stream>>>(
      DELTA, XSb, SSMB, A_log, Dp, AGG_H, Yb);

  // 6) out = y @ W_out  (M=2048 N=1024 K=2048, TN=64, splitK=1) -> d_out
  mgemm<1, 64, 0><<<dim3(16, 16, 1), blk, 0, stream>>>(
      Yb, DI, WoutT, DI, out, DMODEL, DI);
}

// Round 9
// 241.673 us; speedup vs baseline: 1.0243x; 1.0243x over previous
//
#include <hip/hip_runtime.h>
#include <math.h>

// Problem constants
#define BATCH   2
#define LSEQ    1024
#define DMODEL  1024
#define DI      2048      // D_INNER
#define NSTATE  16
#define DTR     64        // DT_RANK
#define SSMP    128       // padded ssm width (96 -> 128); B at +64, C at +80
#define MROWS   2048      // BATCH*LSEQ
#define CHUNK   32
#define NCHUNK  32        // LSEQ / CHUNK

typedef unsigned short u16;
typedef __attribute__((ext_vector_type(8))) short short8;   // 8 bf16 (4 VGPRs)
typedef __attribute__((ext_vector_type(4))) float f32x4;

__device__ __forceinline__ float silu_f(float x) {
  return x / (1.f + __expf(-x));
}
__device__ __forceinline__ float softplus_f(float x) {
  return fmaxf(x, 0.f) + __logf(1.f + __expf(-fabsf(x)));
}
__device__ __forceinline__ u16 f2bf(float f) {   // RNE
  unsigned u = __float_as_uint(f);
  return (u16)((u + 0x7fffu + ((u >> 16) & 1u)) >> 16);
}
__device__ __forceinline__ float bf2f(u16 v) {
  return __uint_as_float(((unsigned)v) << 16);
}

// async global -> LDS, 16 B per lane; LDS dest = wave-uniform base + lane*16
__device__ __forceinline__ void gload_lds16(const u16* g, u16* l) {
  __builtin_amdgcn_global_load_lds(
      (const __attribute__((address_space(1))) unsigned int*)(const void*)g,
      (__attribute__((address_space(3))) unsigned int*)(void*)l, 16, 0, 0);
}

// ---------------------------------------------------------------------------
// Fused preprocessing: one kernel, block-range dispatch.
//   [0,2048)        : cvt x fp32->bf16 (2M elems, x4 vec)
//   [2048,4096)     : transpose W_in   [1024][2048] -> WinT  [2048][1024]
//   [4096,4288)     : transpose W_x    [2048][96]   -> WxT   [96 of 128][2048]
//   [4288,4352)     : zero WxT rows 96..127
//   [4352,6400)     : transpose W_out  [2048][1024] -> WoutT [1024][2048]
// ---------------------------------------------------------------------------
__device__ __forceinline__ void transpose_dev(
    float (*t)[33], const float* __restrict__ in, u16* __restrict__ out,
    int R, int C, int bx, int by, int tid)
{
  const int tx = tid & 31, ty = tid >> 5;          // 32 x 8
  const int c0 = bx * 32, r0 = by * 32;
#pragma unroll
  for (int k = 0; k < 4; ++k)
    t[ty + 8 * k][tx] = in[(size_t)(r0 + ty + 8 * k) * C + c0 + tx];
  __syncthreads();
#pragma unroll
  for (int k = 0; k < 4; ++k)
    out[(size_t)(c0 + ty + 8 * k) * R + r0 + tx] = f2bf(t[tx][ty + 8 * k]);
}

__global__ __launch_bounds__(256) void prep_kernel(
    const float* __restrict__ x, const float* __restrict__ W_in,
    const float* __restrict__ W_x, const float* __restrict__ W_out,
    u16* __restrict__ x_bf, u16* __restrict__ WinT, u16* __restrict__ WxT,
    u16* __restrict__ WoutT)
{
  __shared__ float ts[32][33];
  const int tid = threadIdx.x;
  int bi = blockIdx.x;
  if (bi < 2048) {                      // cvt x
    const int i = (bi * 256 + tid) * 4;
    float4 v = *(const float4*)(x + i);
    ushort4 o;
    o.x = f2bf(v.x); o.y = f2bf(v.y); o.z = f2bf(v.z); o.w = f2bf(v.w);
    *(ushort4*)(x_bf + i) = o;
    return;
  }
  bi -= 2048;
  if (bi < 2048) {                      // W_in: grid (64, 32)
    transpose_dev(ts, W_in, WinT, 1024, 2048, bi & 63, bi >> 6, tid);
    return;
  }
  bi -= 2048;
  if (bi < 192) {                       // W_x: grid (3, 64)
    transpose_dev(ts, W_x, WxT, 2048, 96, bi % 3, bi / 3, tid);
    return;
  }
  bi -= 192;
  if (bi < 64) {                        // zero WxT rows 96..127 (64K u16)
    const int i = (bi * 256 + tid) * 4;
    *(ushort4*)(WxT + 96 * 2048 + i) = make_ushort4(0, 0, 0, 0);
    return;
  }
  bi -= 64;
  {                                     // W_out: grid (32, 64)
    transpose_dev(ts, W_out, WoutT, 2048, 1024, bi & 31, bi >> 5, tid);
  }
}

// ---------------------------------------------------------------------------
// bf16 MFMA GEMM, m97-style: C[M x TNxgrid] = A[M x K] * Bt[N x K]^T
// Tile 128(M) x TN(N), BK=32, 256 threads = 4 waves.
// Staging: global_load_lds dwordx4 with store-side XOR chunk swizzle.
// SPLITK>1: deterministic partials at C + z*(gridDim.y*128*ldc).
// OBF==1: output bf16 (u16) instead of fp32.
// ---------------------------------------------------------------------------
template<int SPLITK, int TN, int OBF>
__global__ __launch_bounds__(256) void mgemm(
    const u16* __restrict__ A, int lda,
    const u16* __restrict__ Bt, int ldb,
    void* __restrict__ Cv, int ldc, int K)
{
  constexpr int WI = (TN == 128) ? 4 : 2;   // a-frags per wave
  __shared__ u16 Al[128 * 32];
  __shared__ u16 Bl[TN * 32];
  const int tid = threadIdx.x;
  const int bm = blockIdx.y * 128;
  const int bn = blockIdx.x * TN;
  const int lane = tid & 63;
  const int w = tid >> 6;
  const int wm = (TN == 128) ? (w & 1) * 64 : w * 32;
  const int wn = (TN == 128) ? (w >> 1) * 64 : 0;
  const int quad = lane >> 4;
  const int lm = lane & 15;

  const int Kper = K / SPLITK;
  const int k_beg = blockIdx.z * Kper;

  const int clog8 = (((lane & 3) ^ ((lane >> 3) & 3)) << 3);  // u16 offset
  const int rA = w * 32 + (lane >> 2);
  const int rB = ((TN == 128) ? w * 32 : w * 16) + (lane >> 2);
  const u16* gA0 = A + (size_t)(bm + rA) * lda + k_beg + clog8;
  const u16* gA1 = gA0 + (size_t)16 * lda;
  const u16* gB0 = Bt + (size_t)(bn + rB) * ldb + k_beg + clog8;
  const u16* gB1 = gB0 + (size_t)16 * ldb;
  u16* lA0 = &Al[(w * 32) * 32];
  u16* lA1 = &Al[(w * 32 + 16) * 32];
  u16* lB0 = &Bl[(((TN == 128) ? w * 32 : w * 16)) * 32];
  u16* lB1 = &Bl[((TN == 128) ? (w * 32 + 16) : 0) * 32];

  const int cph8 = ((quad ^ ((lm >> 1) & 3)) << 3);

  f32x4 acc[WI][4] = {};

  for (int ks = 0; ks < Kper; ks += 32) {
    gload_lds16(gA0, lA0);
    gload_lds16(gA1, lA1);
    gload_lds16(gB0, lB0);
    if (TN == 128) gload_lds16(gB1, lB1);
    gA0 += 32; gA1 += 32; gB0 += 32; gB1 += 32;
    __syncthreads();

    short8 a[WI], b[4];
#pragma unroll
    for (int i = 0; i < WI; ++i)
      a[i] = *(const short8*)&Al[(wm + i * 16 + lm) * 32 + cph8];
#pragma unroll
    for (int j = 0; j < 4; ++j)
      b[j] = *(const short8*)&Bl[(wn + j * 16 + lm) * 32 + cph8];
#pragma unroll
    for (int i = 0; i < WI; ++i)
#pragma unroll
      for (int j = 0; j < 4; ++j)
        acc[i][j] = __builtin_amdgcn_mfma_f32_16x16x32_bf16(a[i], b[j], acc[i][j], 0, 0, 0);
    __syncthreads();
  }

#pragma unroll
  for (int i = 0; i < WI; ++i) {
#pragma unroll
    for (int r = 0; r < 4; ++r) {
      const int row = bm + wm + i * 16 + quad * 4 + r;
#pragma unroll
      for (int j = 0; j < 4; ++j) {
        const int col = bn + wn + j * 16 + lm;
        float v = acc[i][j][r];
        if (OBF) {
          ((u16*)Cv)[(size_t)row * ldc + col] = f2bf(v);
        } else {
          float* Cz = (float*)Cv;
          if (SPLITK > 1) Cz += (size_t)blockIdx.z * gridDim.y * 128 * ldc;
          Cz[(size_t)row * ldc + col] = v;
        }
      }
    }
  }
}

// ---------------------------------------------------------------------------
// Reduce gemm3's 8 split-K partials -> SSMB fp32.
// ---------------------------------------------------------------------------
__global__ __launch_bounds__(256) void reduce3(
    const float* __restrict__ P3, float* __restrict__ SSMB)
{
  const int t = blockIdx.x * 256 + threadIdx.x;   // over 2048*128
  float s = 0.f;
#pragma unroll
  for (int z = 0; z < 8; ++z) s += P3[(size_t)z * (MROWS * SSMP) + t];
  SSMB[t] = s;
}

// ---------------------------------------------------------------------------
// DELTA = softplus(SSMB[:, :64] @ W_dt + b_dt), fp32 out.
// Block = 8 rows x 1024 cols (grid 512, 2 blocks/CU); thread = 8r x 4c = 32 acc
// (8x8 spilled at 256 threads: R8 measured VGPR=52 < 64 acc -> 47us stall).
// dt rows broadcast from LDS; W_dt streamed fp32 row-wise (coalesced).
// ---------------------------------------------------------------------------
__global__ __launch_bounds__(256) void delta_kernel(
    const float* __restrict__ SSMB, const float* __restrict__ W_dt,
    const float* __restrict__ b_dt, float* __restrict__ DELTA)
{
  __shared__ float dts[8][64];
  const int tid = threadIdx.x;
  const int r0 = (blockIdx.x >> 1) * 8;
  const int c0 = (blockIdx.x & 1) * 1024 + tid * 4;
  {
    const int r = tid >> 5, k = (tid & 31) * 2;   // 512 elems, 2/thread
    const float2 v = *(const float2*)&SSMB[(size_t)(r0 + r) * SSMP + k];
    dts[r][k] = v.x; dts[r][k + 1] = v.y;
  }
  __syncthreads();

  float acc[8][4];
  {
    const float4 bv = *(const float4*)&b_dt[c0];
#pragma unroll
    for (int r = 0; r < 8; ++r) {
      acc[r][0] = bv.x; acc[r][1] = bv.y; acc[r][2] = bv.z; acc[r][3] = bv.w;
    }
  }

#pragma unroll 4
  for (int k = 0; k < DTR; ++k) {
    const float4 w = *(const float4*)&W_dt[(size_t)k * DI + c0];
#pragma unroll
    for (int r = 0; r < 8; ++r) {
      const float d = dts[r][k];
      acc[r][0] = fmaf(w.x, d, acc[r][0]);
      acc[r][1] = fmaf(w.y, d, acc[r][1]);
      acc[r][2] = fmaf(w.z, d, acc[r][2]);
      acc[r][3] = fmaf(w.w, d, acc[r][3]);
    }
  }

#pragma unroll
  for (int r = 0; r < 8; ++r) {
    float4 o;
    o.x = softplus_f(acc[r][0]); o.y = softplus_f(acc[r][1]);
    o.z = softplus_f(acc[r][2]); o.w = softplus_f(acc[r][3]);
    *(float4*)&DELTA[(size_t)(r0 + r) * DI + c0] = o;
  }
}

// ---------------------------------------------------------------------------
// Depthwise causal conv (k=4) + bias + SiLU. Reads XVb bf16, writes XSb bf16.
// ---------------------------------------------------------------------------
__global__ __launch_bounds__(256) void conv_silu_kernel(
    const u16* __restrict__ XVb, const float* __restrict__ cw,
    const float* __restrict__ cb, u16* __restrict__ XSb)
{
  const int idx = blockIdx.x * 256 + threadIdx.x;   // over B*L*DI
  const int d = idx & (DI - 1);
  const int bl = idx >> 11;
  const int l = bl & (LSEQ - 1);
  const float w0 = cw[d * 4 + 0], w1 = cw[d * 4 + 1];
  const float w2 = cw[d * 4 + 2], w3 = cw[d * 4 + 3];
  const u16* p = XVb + (size_t)idx;
  float acc = cb[d];
  acc = fmaf(w3, bf2f(p[0]), acc);
  if (l >= 1) acc = fmaf(w2, bf2f(p[-DI]), acc);
  if (l >= 2) acc = fmaf(w1, bf2f(p[-2 * DI]), acc);
  if (l >= 3) acc = fmaf(w0, bf2f(p[-3 * DI]), acc);
  XSb[idx] = f2bf(silu_f(acc));
}

// ---------------------------------------------------------------------------
// Chunked parallel scan, register-state version (one thread per (b,chunk,d)).
// ---------------------------------------------------------------------------
__global__ __launch_bounds__(256) void scan_pass1(
    const float* __restrict__ DELTA, const u16* __restrict__ XSb,
    const float* __restrict__ SSMB, const float* __restrict__ A_log,
    float* __restrict__ AGG_A, float* __restrict__ AGG_H)
{
  __shared__ float Bs[CHUNK * 16];
  const int tid = threadIdx.x;
  const int db = blockIdx.x & 7;
  const int c  = (blockIdx.x >> 3) & (NCHUNK - 1);
  const int b  = blockIdx.x >> 8;
  const int d  = db * 256 + tid;
  const int l0 = c * CHUNK;

  for (int i = tid; i < CHUNK * 16; i += 256) {
    const int l = i >> 4, n = i & 15;
    Bs[i] = SSMB[((size_t)(b * LSEQ + l0 + l)) * SSMP + DTR + n];
  }
  __syncthreads();

  float An[16];
  {
    const float* ar = A_log + d * 16;
#pragma unroll
    for (int n = 0; n < 16; ++n) An[n] = -__expf(ar[n]);
  }

  float h[16];
#pragma unroll
  for (int n = 0; n < 16; ++n) h[n] = 0.f;
  float S = 0.f;

  const float* dp = DELTA + ((size_t)(b * LSEQ + l0)) * DI + d;
  const u16*   xp = XSb   + ((size_t)(b * LSEQ + l0)) * DI + d;

  for (int l = 0; l < CHUNK; ++l) {
    const float delta = *dp; dp += DI;
    const float xv = bf2f(*xp); xp += DI;
    S += delta;
    const float dt = delta * xv;
    const f32x4 b0 = *(const f32x4*)&Bs[l * 16];
    const f32x4 b1 = *(const f32x4*)&Bs[l * 16 + 4];
    const f32x4 b2 = *(const f32x4*)&Bs[l * 16 + 8];
    const f32x4 b3 = *(const f32x4*)&Bs[l * 16 + 12];
#pragma unroll
    for (int n = 0; n < 16; ++n) {
      const float Bv = (n < 4) ? b0[n & 3] : (n < 8) ? b1[n & 3] : (n < 12) ? b2[n & 3] : b3[n & 3];
      const float dA = __expf(delta * An[n]);
      h[n] = fmaf(dA, h[n], Bv * dt);
    }
  }

  const size_t base = (((size_t)(b * NCHUNK + c) * DI + d) << 4);
  f32x4 oa[4], oh[4];
#pragma unroll
  for (int q = 0; q < 4; ++q) {
#pragma unroll
    for (int r = 0; r < 4; ++r) {
      oa[q][r] = __expf(An[q * 4 + r] * S);
      oh[q][r] = h[q * 4 + r];
    }
    *(f32x4*)&AGG_A[base + q * 4] = oa[q];
    *(f32x4*)&AGG_H[base + q * 4] = oh[q];
  }
}

// In-place prefix over chunks: AGG_H[ai] <- exclusive prefix (h_init).
__global__ __launch_bounds__(256) void scan_pass2(
    const float* __restrict__ AGG_A, float* __restrict__ AGG_H)
{
  const int t = blockIdx.x * 256 + threadIdx.x;   // over B*DI*NSTATE
  const int dn = t & (DI * NSTATE - 1);
  const int b = t >> 15;
  size_t ai = (size_t)b * NCHUNK * DI * NSTATE + dn;
  const size_t stride = (size_t)DI * NSTATE;
  float h = 0.f;
#pragma unroll
  for (int c = 0; c < NCHUNK; ++c) {
    const float a = AGG_A[ai];
    const float hp = AGG_H[ai];
    AGG_H[ai] = h;
    h = fmaf(a, h, hp);
    ai += stride;
  }
}

__global__ __launch_bounds__(256) void scan_pass3(
    const float* __restrict__ DELTA, const u16* __restrict__ XSb,
    const float* __restrict__ SSMB, const float* __restrict__ A_log,
    const float* __restrict__ Dp, const float* __restrict__ HINIT,
    u16* __restrict__ Yb)
{
  __shared__ float Bs[CHUNK * 16];
  __shared__ float Cs[CHUNK * 16];
  const int tid = threadIdx.x;
  const int db = blockIdx.x & 7;
  const int c  = (blockIdx.x >> 3) & (NCHUNK - 1);
  const int b  = blockIdx.x >> 8;
  const int d  = db * 256 + tid;
  const int l0 = c * CHUNK;

  for (int i = tid; i < CHUNK * 16; i += 256) {
    const int l = i >> 4, n = i & 15;
    const size_t row = ((size_t)(b * LSEQ + l0 + l)) * SSMP;
    Bs[i] = SSMB[row + DTR + n];
    Cs[i] = SSMB[row + DTR + NSTATE + n];
  }
  __syncthreads();

  float An[16];
  {
    const float* ar = A_log + d * 16;
#pragma unroll
    for (int n = 0; n < 16; ++n) An[n] = -__expf(ar[n]);
  }
  const float Dd = Dp[d];

  const size_t base = (((size_t)(b * NCHUNK + c) * DI + d) << 4);
  float h[16];
#pragma unroll
  for (int q = 0; q < 4; ++q) {
    const f32x4 hv = *(const f32x4*)&HINIT[base + q * 4];
#pragma unroll
    for (int r = 0; r < 4; ++r) h[q * 4 + r] = hv[r];
  }

  const float* dp = DELTA + ((size_t)(b * LSEQ + l0)) * DI + d;
  const u16*   xp = XSb   + ((size_t)(b * LSEQ + l0)) * DI + d;
  u16*         yp = Yb    + ((size_t)(b * LSEQ + l0)) * DI + d;

  for (int l = 0; l < CHUNK; ++l) {
    const float delta = *dp; dp += DI;
    const float xv = bf2f(*xp); xp += DI;
    const float dt = delta * xv;
    float y = xv * Dd;
    const f32x4 b0 = *(const f32x4*)&Bs[l * 16];
    const f32x4 b1 = *(const f32x4*)&Bs[l * 16 + 4];
    const f32x4 b2 = *(const f32x4*)&Bs[l * 16 + 8];
    const f32x4 b3 = *(const f32x4*)&Bs[l * 16 + 12];
    const f32x4 c0 = *(const f32x4*)&Cs[l * 16];
    const f32x4 c1 = *(const f32x4*)&Cs[l * 16 + 4];
    const f32x4 c2 = *(const f32x4*)&Cs[l * 16 + 8];
    const f32x4 c3 = *(const f32x4*)&Cs[l * 16 + 12];
#pragma unroll
    for (int n = 0; n < 16; ++n) {
      const float Bv = (n < 4) ? b0[n & 3] : (n < 8) ? b1[n & 3] : (n < 12) ? b2[n & 3] : b3[n & 3];
      const float Cv = (n < 4) ? c0[n & 3] : (n < 8) ? c1[n & 3] : (n < 12) ? c2[n & 3] : c3[n & 3];
      const float dA = __expf(delta * An[n]);
      h[n] = fmaf(dA, h[n], Bv * dt);
      y = fmaf(h[n], Cv, y);
    }
    *yp = f2bf(y); yp += DI;
  }
}

// ---------------------------------------------------------------------------
extern "C" void kernel_launch(void* const* d_in, const int* in_sizes, int n_in,
                              void* d_out, int out_size, void* d_ws, size_t ws_size,
                              hipStream_t stream)
{
  const float* x      = (const float*)d_in[0];
  const float* W_in   = (const float*)d_in[1];
  const float* conv_w = (const float*)d_in[2];
  const float* conv_b = (const float*)d_in[3];
  const float* W_x    = (const float*)d_in[4];
  const float* W_dt   = (const float*)d_in[5];
  const float* b_dt   = (const float*)d_in[6];
  const float* A_log  = (const float*)d_in[7];
  const float* Dp     = (const float*)d_in[8];
  const float* W_out  = (const float*)d_in[9];
  float* out = (float*)d_out;
  char* W = (char*)d_ws;

  const size_t MB = 1u << 20;
  // byte layout (46 MB), time-multiplexed:
  // [0,8)   : XVb bf16 (gemm1->conv) -> AGG_A (scan1->2) -> Yb (scan3->gemm6)
  // [8,16)  : AGG_H (scan1->3, in-place HINIT after pass2)
  // [16,32) : x_bf[16,20)+WinT[20,24) (prep->gemm1) -> P3 8MB [16,24)
  //           (gemm3->reduce3) -> DELTA 16MB [16,32) (delta->scan)
  // [32,40) : XSb bf16
  // [40,41) : SSMB fp32 [2048][128]
  // [41,45) : WoutT
  // [45,46) : WxT
  u16*   XVb   = (u16*)  (W + 0);
  float* AGG_A = (float*)(W + 0);
  u16*   Yb    = (u16*)  (W + 0);
  float* AGG_H = (float*)(W + 8 * MB);
  u16*   x_bf  = (u16*)  (W + 16 * MB);
  u16*   WinT  = (u16*)  (W + 20 * MB);
  float* P3    = (float*)(W + 16 * MB);
  float* DELTA = (float*)(W + 16 * MB);
  u16*   XSb   = (u16*)  (W + 32 * MB);
  float* SSMB  = (float*)(W + 40 * MB);
  u16*   WoutT = (u16*)  (W + 41 * MB);
  u16*   WxT   = (u16*)  (W + 45 * MB);

  dim3 blk(256);

  // 0) fused preprocessing (cvt + 3 transposes + WxT pad-zero)
  prep_kernel<<<dim3(6400), blk, 0, stream>>>(
      x, W_in, W_x, W_out, x_bf, WinT, WxT, WoutT);

  // 1) xv = x @ W_in  (M=2048 N=2048 K=1024), TN=64, bf16 out -> XVb
  mgemm<1, 64, 1><<<dim3(32, 16, 1), blk, 0, stream>>>(
      x_bf, DMODEL, WinT, DMODEL, XVb, DI, DMODEL);

  // 2) conv + silu (bf16 in) -> XSb bf16
  conv_silu_kernel<<<dim3((BATCH * LSEQ * DI) / 256), blk, 0, stream>>>(
      XVb, conv_w, conv_b, XSb);

  // 3) ssm partials (M=2048 N=128pad K=2048, TN=64 splitK=8) -> P3, reduce
  mgemm<8, 64, 0><<<dim3(2, 16, 8), blk, 0, stream>>>(
      XSb, DI, WxT, DI, P3, SSMP, DI);
  reduce3<<<dim3(MROWS * SSMP / 256), blk, 0, stream>>>(P3, SSMB);

  // 4) delta = softplus(ssm[:, :64] @ W_dt + b_dt) -> DELTA fp32 (VALU kernel)
  delta_kernel<<<dim3(MROWS / 4), blk, 0, stream>>>(SSMB, W_dt, b_dt, DELTA);

  // 5) chunked scan (register-state)
  scan_pass1<<<dim3(BATCH * NCHUNK * (DI / 256)), blk, 0, stream>>>(
      DELTA, XSb, SSMB, A_log, AGG_A, AGG_H);
  scan_pass2<<<dim3((BATCH * DI * NSTATE) / 256), blk, 0, stream>>>(
      AGG_A, AGG_H);
  scan_pass3<<<dim3(BATCH * NCHUNK * (DI / 256)), blk, 0, stream>>>(
      DELTA, XSb, SSMB, A_log, Dp, AGG_H, Yb);

  // 6) out = y @ W_out  (M=2048 N=1024 K=2048, TN=64, splitK=1) -> d_out
  mgemm<1, 64, 0><<<dim3(16, 16, 1), blk, 0, stream>>>(
      Yb, DI, WoutT, DI, out, DMODEL, DI);
}

// Round 10
// 225.834 us; speedup vs baseline: 1.0962x; 1.0701x over previous
//
#include <hip/hip_runtime.h>
#include <math.h>

// Problem constants
#define BATCH   2
#define LSEQ    1024
#define DMODEL  1024
#define DI      2048      // D_INNER
#define NSTATE  16
#define DTR     64        // DT_RANK
#define SSMP    128       // padded ssm width (96 -> 128); B at +64, C at +80
#define MROWS   2048      // BATCH*LSEQ
#define CHUNK   32
#define NCHUNK  32        // LSEQ / CHUNK

typedef unsigned short u16;
typedef __attribute__((ext_vector_type(8))) short short8;   // 8 bf16 (4 VGPRs)
typedef __attribute__((ext_vector_type(4))) float f32x4;

__device__ __forceinline__ float silu_f(float x) {
  return x / (1.f + __expf(-x));
}
__device__ __forceinline__ float softplus_f(float x) {
  return fmaxf(x, 0.f) + __logf(1.f + __expf(-fabsf(x)));
}
__device__ __forceinline__ u16 f2bf(float f) {   // RNE
  unsigned u = __float_as_uint(f);
  return (u16)((u + 0x7fffu + ((u >> 16) & 1u)) >> 16);
}
__device__ __forceinline__ float bf2f(u16 v) {
  return __uint_as_float(((unsigned)v) << 16);
}

// async global -> LDS, 16 B per lane; LDS dest = wave-uniform base + lane*16
__device__ __forceinline__ void gload_lds16(const u16* g, u16* l) {
  __builtin_amdgcn_global_load_lds(
      (const __attribute__((address_space(1))) unsigned int*)(const void*)g,
      (__attribute__((address_space(3))) unsigned int*)(void*)l, 16, 0, 0);
}

// ---------------------------------------------------------------------------
// Fused preprocessing (one kernel, block-range dispatch).
// ---------------------------------------------------------------------------
__device__ __forceinline__ void transpose_dev(
    float (*t)[33], const float* __restrict__ in, u16* __restrict__ out,
    int R, int C, int bx, int by, int tid)
{
  const int tx = tid & 31, ty = tid >> 5;          // 32 x 8
  const int c0 = bx * 32, r0 = by * 32;
#pragma unroll
  for (int k = 0; k < 4; ++k)
    t[ty + 8 * k][tx] = in[(size_t)(r0 + ty + 8 * k) * C + c0 + tx];
  __syncthreads();
#pragma unroll
  for (int k = 0; k < 4; ++k)
    out[(size_t)(c0 + ty + 8 * k) * R + r0 + tx] = f2bf(t[tx][ty + 8 * k]);
}

__global__ __launch_bounds__(256) void prep_kernel(
    const float* __restrict__ x, const float* __restrict__ W_in,
    const float* __restrict__ W_x, const float* __restrict__ W_out,
    u16* __restrict__ x_bf, u16* __restrict__ WinT, u16* __restrict__ WxT,
    u16* __restrict__ WoutT)
{
  __shared__ float ts[32][33];
  const int tid = threadIdx.x;
  int bi = blockIdx.x;
  if (bi < 2048) {                      // cvt x
    const int i = (bi * 256 + tid) * 4;
    float4 v = *(const float4*)(x + i);
    ushort4 o;
    o.x = f2bf(v.x); o.y = f2bf(v.y); o.z = f2bf(v.z); o.w = f2bf(v.w);
    *(ushort4*)(x_bf + i) = o;
    return;
  }
  bi -= 2048;
  if (bi < 2048) {                      // W_in: grid (64, 32)
    transpose_dev(ts, W_in, WinT, 1024, 2048, bi & 63, bi >> 6, tid);
    return;
  }
  bi -= 2048;
  if (bi < 192) {                       // W_x: grid (3, 64)
    transpose_dev(ts, W_x, WxT, 2048, 96, bi % 3, bi / 3, tid);
    return;
  }
  bi -= 192;
  if (bi < 64) {                        // zero WxT rows 96..127
    const int i = (bi * 256 + tid) * 4;
    *(ushort4*)(WxT + 96 * 2048 + i) = make_ushort4(0, 0, 0, 0);
    return;
  }
  bi -= 64;
  {                                     // W_out: grid (32, 64)
    transpose_dev(ts, W_out, WoutT, 2048, 1024, bi & 31, bi >> 5, tid);
  }
}

// ---------------------------------------------------------------------------
// bf16 MFMA GEMM, m97-style: C[M x TNxgrid] = A[M x K] * Bt[N x K]^T
// Tile 128(M) x TN(N), BK=32, 256 threads = 4 waves.
// Staging: global_load_lds dwordx4 with store-side XOR chunk swizzle.
// SPLITK>1: deterministic partials at C + z*(gridDim.y*128*ldc).
// OBF==1: output bf16. CONV==1 (TN=64 only): epilogue routes the xv tile
// through LDS, applies causal depthwise conv(4)+bias+SiLU in-tile (rows>=3),
// writes XSb (=Cv) bf16; boundary rows {0,1,2,125,126,127} of each tile are
// emitted raw to xvb for the fixup kernel.
// ---------------------------------------------------------------------------
template<int SPLITK, int TN, int OBF, int CONV>
__global__ __launch_bounds__(256) void mgemm(
    const u16* __restrict__ A, int lda,
    const u16* __restrict__ Bt, int ldb,
    void* __restrict__ Cv, int ldc, int K,
    const float* __restrict__ cw, const float* __restrict__ cb,
    u16* __restrict__ xvb)
{
  constexpr int WI = (TN == 128) ? 4 : 2;   // a-frags per wave
  __shared__ u16 Al[128 * 32];
  __shared__ u16 Bl[TN * 32];
  const int tid = threadIdx.x;
  const int bm = blockIdx.y * 128;
  const int bn = blockIdx.x * TN;
  const int lane = tid & 63;
  const int w = tid >> 6;
  const int wm = (TN == 128) ? (w & 1) * 64 : w * 32;
  const int wn = (TN == 128) ? (w >> 1) * 64 : 0;
  const int quad = lane >> 4;
  const int lm = lane & 15;

  const int Kper = K / SPLITK;
  const int k_beg = blockIdx.z * Kper;

  const int clog8 = (((lane & 3) ^ ((lane >> 3) & 3)) << 3);  // u16 offset
  const int rA = w * 32 + (lane >> 2);
  const int rB = ((TN == 128) ? w * 32 : w * 16) + (lane >> 2);
  const u16* gA0 = A + (size_t)(bm + rA) * lda + k_beg + clog8;
  const u16* gA1 = gA0 + (size_t)16 * lda;
  const u16* gB0 = Bt + (size_t)(bn + rB) * ldb + k_beg + clog8;
  const u16* gB1 = gB0 + (size_t)16 * ldb;
  u16* lA0 = &Al[(w * 32) * 32];
  u16* lA1 = &Al[(w * 32 + 16) * 32];
  u16* lB0 = &Bl[(((TN == 128) ? w * 32 : w * 16)) * 32];
  u16* lB1 = &Bl[((TN == 128) ? (w * 32 + 16) : 0) * 32];

  const int cph8 = ((quad ^ ((lm >> 1) & 3)) << 3);

  f32x4 acc[WI][4] = {};

  for (int ks = 0; ks < Kper; ks += 32) {
    gload_lds16(gA0, lA0);
    gload_lds16(gA1, lA1);
    gload_lds16(gB0, lB0);
    if (TN == 128) gload_lds16(gB1, lB1);
    gA0 += 32; gA1 += 32; gB0 += 32; gB1 += 32;
    __syncthreads();

    short8 a[WI], b[4];
#pragma unroll
    for (int i = 0; i < WI; ++i)
      a[i] = *(const short8*)&Al[(wm + i * 16 + lm) * 32 + cph8];
#pragma unroll
    for (int j = 0; j < 4; ++j)
      b[j] = *(const short8*)&Bl[(wn + j * 16 + lm) * 32 + cph8];
#pragma unroll
    for (int i = 0; i < WI; ++i)
#pragma unroll
      for (int j = 0; j < 4; ++j)
        acc[i][j] = __builtin_amdgcn_mfma_f32_16x16x32_bf16(a[i], b[j], acc[i][j], 0, 0, 0);
    __syncthreads();
  }

  if constexpr (CONV) {
    // ---- fused conv epilogue (TN==64) ----
    __shared__ u16 xvs[128 * 68];   // stride 68 u16 = 136 B (8B-aligned rows)
#pragma unroll
    for (int i = 0; i < WI; ++i)
#pragma unroll
      for (int r = 0; r < 4; ++r)
#pragma unroll
        for (int j = 0; j < 4; ++j)
          xvs[(wm + i * 16 + quad * 4 + r) * 68 + wn + j * 16 + lm] =
              f2bf(acc[i][j][r]);
    __syncthreads();

    const int rblk = tid >> 4;          // 0..15 -> 8 rows each
    const int c4 = (tid & 15) * 4;      // 0..60
    const int dg = bn + c4;
    float cwv[4][4], cbv[4];
#pragma unroll
    for (int cc = 0; cc < 4; ++cc) {
      const float4 wv = *(const float4*)&cw[(size_t)(dg + cc) * 4];
      cwv[cc][0] = wv.x; cwv[cc][1] = wv.y; cwv[cc][2] = wv.z; cwv[cc][3] = wv.w;
      cbv[cc] = cb[dg + cc];
    }
    float a3[4], a2[4], a1[4], a0[4];
    auto ldrow = [&](int r, float* o) {
      if (r >= 0) {
        const ushort4 u = *(const ushort4*)&xvs[r * 68 + c4];
        o[0] = bf2f(u.x); o[1] = bf2f(u.y); o[2] = bf2f(u.z); o[3] = bf2f(u.w);
      } else {
        o[0] = o[1] = o[2] = o[3] = 0.f;
      }
    };
    ldrow(rblk * 8 - 3, a3);
    ldrow(rblk * 8 - 2, a2);
    ldrow(rblk * 8 - 1, a1);
    u16* XSb = (u16*)Cv;
#pragma unroll
    for (int rr = 0; rr < 8; ++rr) {
      const int lr = rblk * 8 + rr;
      const int m = bm + lr;
      ldrow(lr, a0);
      if (lr >= 3) {
        ushort4 o;
        u16* oe = (u16*)&o;
#pragma unroll
        for (int cc = 0; cc < 4; ++cc) {
          float s = cbv[cc];
          s = fmaf(cwv[cc][0], a3[cc], s);
          s = fmaf(cwv[cc][1], a2[cc], s);
          s = fmaf(cwv[cc][2], a1[cc], s);
          s = fmaf(cwv[cc][3], a0[cc], s);
          oe[cc] = f2bf(silu_f(s));
        }
        *(ushort4*)&XSb[(size_t)m * ldc + dg] = o;
      }
      if (lr < 3 || lr >= 125) {
        *(ushort4*)&xvb[(size_t)m * ldc + dg] = *(const ushort4*)&xvs[lr * 68 + c4];
      }
#pragma unroll
      for (int cc = 0; cc < 4; ++cc) { a3[cc] = a2[cc]; a2[cc] = a1[cc]; a1[cc] = a0[cc]; }
    }
  } else {
#pragma unroll
    for (int i = 0; i < WI; ++i) {
#pragma unroll
      for (int r = 0; r < 4; ++r) {
        const int row = bm + wm + i * 16 + quad * 4 + r;
#pragma unroll
        for (int j = 0; j < 4; ++j) {
          const int col = bn + wn + j * 16 + lm;
          float v = acc[i][j][r];
          if (OBF) {
            ((u16*)Cv)[(size_t)row * ldc + col] = f2bf(v);
          } else {
            float* Cz = (float*)Cv;
            if (SPLITK > 1) Cz += (size_t)blockIdx.z * gridDim.y * 128 * ldc;
            Cz[(size_t)row * ldc + col] = v;
          }
        }
      }
    }
  }
}

// ---------------------------------------------------------------------------
// Conv fixup for tile-boundary rows: (m & 127) < 3. Reads XVb boundary rows
// (written by gemm1's conv epilogue), writes XSb. 48 rows x 2048 cols.
// ---------------------------------------------------------------------------
__global__ __launch_bounds__(256) void fixup_kernel(
    const u16* __restrict__ XVb, const float* __restrict__ cw,
    const float* __restrict__ cb, u16* __restrict__ XSb)
{
  const int t = blockIdx.x * 256 + threadIdx.x;   // 24576 threads
  const int row_id = t >> 9;         // 0..47
  const int c4 = (t & 511) * 4;
  const int tile = row_id / 3, sub = row_id % 3;
  const int m = tile * 128 + sub;
  const int l = m & (LSEQ - 1);
  float s[4];
  float cwk[4][4];
#pragma unroll
  for (int cc = 0; cc < 4; ++cc) {
    const float4 wv = *(const float4*)&cw[(size_t)(c4 + cc) * 4];
    cwk[cc][0] = wv.x; cwk[cc][1] = wv.y; cwk[cc][2] = wv.z; cwk[cc][3] = wv.w;
    s[cc] = cb[c4 + cc];
  }
  const ushort4 u0 = *(const ushort4*)&XVb[(size_t)m * DI + c4];
  s[0] = fmaf(cwk[0][3], bf2f(u0.x), s[0]);
  s[1] = fmaf(cwk[1][3], bf2f(u0.y), s[1]);
  s[2] = fmaf(cwk[2][3], bf2f(u0.z), s[2]);
  s[3] = fmaf(cwk[3][3], bf2f(u0.w), s[3]);
  if (l >= 1) {
    const ushort4 u = *(const ushort4*)&XVb[(size_t)(m - 1) * DI + c4];
    s[0] = fmaf(cwk[0][2], bf2f(u.x), s[0]);
    s[1] = fmaf(cwk[1][2], bf2f(u.y), s[1]);
    s[2] = fmaf(cwk[2][2], bf2f(u.z), s[2]);
    s[3] = fmaf(cwk[3][2], bf2f(u.w), s[3]);
  }
  if (l >= 2) {
    const ushort4 u = *(const ushort4*)&XVb[(size_t)(m - 2) * DI + c4];
    s[0] = fmaf(cwk[0][1], bf2f(u.x), s[0]);
    s[1] = fmaf(cwk[1][1], bf2f(u.y), s[1]);
    s[2] = fmaf(cwk[2][1], bf2f(u.z), s[2]);
    s[3] = fmaf(cwk[3][1], bf2f(u.w), s[3]);
  }
  if (l >= 3) {
    const ushort4 u = *(const ushort4*)&XVb[(size_t)(m - 3) * DI + c4];
    s[0] = fmaf(cwk[0][0], bf2f(u.x), s[0]);
    s[1] = fmaf(cwk[1][0], bf2f(u.y), s[1]);
    s[2] = fmaf(cwk[2][0], bf2f(u.z), s[2]);
    s[3] = fmaf(cwk[3][0], bf2f(u.w), s[3]);
  }
  ushort4 o;
  o.x = f2bf(silu_f(s[0])); o.y = f2bf(silu_f(s[1]));
  o.z = f2bf(silu_f(s[2])); o.w = f2bf(silu_f(s[3]));
  *(ushort4*)&XSb[(size_t)m * DI + c4] = o;
}

// ---------------------------------------------------------------------------
// Fused reduce(P3 splitK=8) + delta. Grid 512: (row-group of 8) x (col half).
// Half-0 blocks also emit SSMB's B/C columns (64..95) -- the only ones the
// scan reads. dt columns (0..63) are reduced into LDS and consumed in-kernel.
// ---------------------------------------------------------------------------
__global__ __launch_bounds__(256) void rd_kernel(
    const float* __restrict__ P3, const float* __restrict__ W_dt,
    const float* __restrict__ b_dt, float* __restrict__ SSMB,
    float* __restrict__ DELTA)
{
  __shared__ float dts[8][64];
  const int tid = threadIdx.x;
  const int r0 = (blockIdx.x >> 1) * 8;
  const int half = blockIdx.x & 1;
  {
    const int i = tid * 2;
    const int r = i >> 6, k = i & 63;
    float sx = 0.f, sy = 0.f;
#pragma unroll
    for (int z = 0; z < 8; ++z) {
      const float2 v = *(const float2*)&P3[(size_t)z * (MROWS * SSMP) +
                                           (size_t)(r0 + r) * SSMP + k];
      sx += v.x; sy += v.y;
    }
    dts[r][k] = sx; dts[r][k + 1] = sy;
  }
  if (half == 0) {
    const int r = tid >> 5, c = DTR + (tid & 31);
    float s = 0.f;
#pragma unroll
    for (int z = 0; z < 8; ++z)
      s += P3[(size_t)z * (MROWS * SSMP) + (size_t)(r0 + r) * SSMP + c];
    SSMB[(size_t)(r0 + r) * SSMP + c] = s;
  }
  __syncthreads();

  const int c0 = half * 1024 + tid * 4;
  float acc[8][4];
  {
    const float4 bv = *(const float4*)&b_dt[c0];
#pragma unroll
    for (int r = 0; r < 8; ++r) {
      acc[r][0] = bv.x; acc[r][1] = bv.y; acc[r][2] = bv.z; acc[r][3] = bv.w;
    }
  }
#pragma unroll 4
  for (int k = 0; k < DTR; ++k) {
    const float4 w = *(const float4*)&W_dt[(size_t)k * DI + c0];
#pragma unroll
    for (int r = 0; r < 8; ++r) {
      const float d = dts[r][k];
      acc[r][0] = fmaf(w.x, d, acc[r][0]);
      acc[r][1] = fmaf(w.y, d, acc[r][1]);
      acc[r][2] = fmaf(w.z, d, acc[r][2]);
      acc[r][3] = fmaf(w.w, d, acc[r][3]);
    }
  }
#pragma unroll
  for (int r = 0; r < 8; ++r) {
    float4 o;
    o.x = softplus_f(acc[r][0]); o.y = softplus_f(acc[r][1]);
    o.z = softplus_f(acc[r][2]); o.w = softplus_f(acc[r][3]);
    *(float4*)&DELTA[(size_t)(r0 + r) * DI + c0] = o;
  }
}

// ---------------------------------------------------------------------------
// Chunked parallel scan, register-state version (one thread per (b,chunk,d)).
// ---------------------------------------------------------------------------
__global__ __launch_bounds__(256) void scan_pass1(
    const float* __restrict__ DELTA, const u16* __restrict__ XSb,
    const float* __restrict__ SSMB, const float* __restrict__ A_log,
    float* __restrict__ AGG_A, float* __restrict__ AGG_H)
{
  __shared__ float Bs[CHUNK * 16];
  const int tid = threadIdx.x;
  const int db = blockIdx.x & 7;
  const int c  = (blockIdx.x >> 3) & (NCHUNK - 1);
  const int b  = blockIdx.x >> 8;
  const int d  = db * 256 + tid;
  const int l0 = c * CHUNK;

  for (int i = tid; i < CHUNK * 16; i += 256) {
    const int l = i >> 4, n = i & 15;
    Bs[i] = SSMB[((size_t)(b * LSEQ + l0 + l)) * SSMP + DTR + n];
  }
  __syncthreads();

  float An[16];
  {
    const float* ar = A_log + d * 16;
#pragma unroll
    for (int n = 0; n < 16; ++n) An[n] = -__expf(ar[n]);
  }

  float h[16];
#pragma unroll
  for (int n = 0; n < 16; ++n) h[n] = 0.f;
  float S = 0.f;

  const float* dp = DELTA + ((size_t)(b * LSEQ + l0)) * DI + d;
  const u16*   xp = XSb   + ((size_t)(b * LSEQ + l0)) * DI + d;

  for (int l = 0; l < CHUNK; ++l) {
    const float delta = *dp; dp += DI;
    const float xv = bf2f(*xp); xp += DI;
    S += delta;
    const float dt = delta * xv;
    const f32x4 b0 = *(const f32x4*)&Bs[l * 16];
    const f32x4 b1 = *(const f32x4*)&Bs[l * 16 + 4];
    const f32x4 b2 = *(const f32x4*)&Bs[l * 16 + 8];
    const f32x4 b3 = *(const f32x4*)&Bs[l * 16 + 12];
#pragma unroll
    for (int n = 0; n < 16; ++n) {
      const float Bv = (n < 4) ? b0[n & 3] : (n < 8) ? b1[n & 3] : (n < 12) ? b2[n & 3] : b3[n & 3];
      const float dA = __expf(delta * An[n]);
      h[n] = fmaf(dA, h[n], Bv * dt);
    }
  }

  const size_t base = (((size_t)(b * NCHUNK + c) * DI + d) << 4);
  f32x4 oa[4], oh[4];
#pragma unroll
  for (int q = 0; q < 4; ++q) {
#pragma unroll
    for (int r = 0; r < 4; ++r) {
      oa[q][r] = __expf(An[q * 4 + r] * S);
      oh[q][r] = h[q * 4 + r];
    }
    *(f32x4*)&AGG_A[base + q * 4] = oa[q];
    *(f32x4*)&AGG_H[base + q * 4] = oh[q];
  }
}

// In-place prefix over chunks: AGG_H[ai] <- exclusive prefix (h_init).
__global__ __launch_bounds__(256) void scan_pass2(
    const float* __restrict__ AGG_A, float* __restrict__ AGG_H)
{
  const int t = blockIdx.x * 256 + threadIdx.x;   // over B*DI*NSTATE
  const int dn = t & (DI * NSTATE - 1);
  const int b = t >> 15;
  size_t ai = (size_t)b * NCHUNK * DI * NSTATE + dn;
  const size_t stride = (size_t)DI * NSTATE;
  float h = 0.f;
#pragma unroll
  for (int c = 0; c < NCHUNK; ++c) {
    const float a = AGG_A[ai];
    const float hp = AGG_H[ai];
    AGG_H[ai] = h;
    h = fmaf(a, h, hp);
    ai += stride;
  }
}

__global__ __launch_bounds__(256) void scan_pass3(
    const float* __restrict__ DELTA, const u16* __restrict__ XSb,
    const float* __restrict__ SSMB, const float* __restrict__ A_log,
    const float* __restrict__ Dp, const float* __restrict__ HINIT,
    u16* __restrict__ Yb)
{
  __shared__ float Bs[CHUNK * 16];
  __shared__ float Cs[CHUNK * 16];
  const int tid = threadIdx.x;
  const int db = blockIdx.x & 7;
  const int c  = (blockIdx.x >> 3) & (NCHUNK - 1);
  const int b  = blockIdx.x >> 8;
  const int d  = db * 256 + tid;
  const int l0 = c * CHUNK;

  for (int i = tid; i < CHUNK * 16; i += 256) {
    const int l = i >> 4, n = i & 15;
    const size_t row = ((size_t)(b * LSEQ + l0 + l)) * SSMP;
    Bs[i] = SSMB[row + DTR + n];
    Cs[i] = SSMB[row + DTR + NSTATE + n];
  }
  __syncthreads();

  float An[16];
  {
    const float* ar = A_log + d * 16;
#pragma unroll
    for (int n = 0; n < 16; ++n) An[n] = -__expf(ar[n]);
  }
  const float Dd = Dp[d];

  const size_t base = (((size_t)(b * NCHUNK + c) * DI + d) << 4);
  float h[16];
#pragma unroll
  for (int q = 0; q < 4; ++q) {
    const f32x4 hv = *(const f32x4*)&HINIT[base + q * 4];
#pragma unroll
    for (int r = 0; r < 4; ++r) h[q * 4 + r] = hv[r];
  }

  const float* dp = DELTA + ((size_t)(b * LSEQ + l0)) * DI + d;
  const u16*   xp = XSb   + ((size_t)(b * LSEQ + l0)) * DI + d;
  u16*         yp = Yb    + ((size_t)(b * LSEQ + l0)) * DI + d;

  for (int l = 0; l < CHUNK; ++l) {
    const float delta = *dp; dp += DI;
    const float xv = bf2f(*xp); xp += DI;
    const float dt = delta * xv;
    float y = xv * Dd;
    const f32x4 b0 = *(const f32x4*)&Bs[l * 16];
    const f32x4 b1 = *(const f32x4*)&Bs[l * 16 + 4];
    const f32x4 b2 = *(const f32x4*)&Bs[l * 16 + 8];
    const f32x4 b3 = *(const f32x4*)&Bs[l * 16 + 12];
    const f32x4 c0 = *(const f32x4*)&Cs[l * 16];
    const f32x4 c1 = *(const f32x4*)&Cs[l * 16 + 4];
    const f32x4 c2 = *(const f32x4*)&Cs[l * 16 + 8];
    const f32x4 c3 = *(const f32x4*)&Cs[l * 16 + 12];
#pragma unroll
    for (int n = 0; n < 16; ++n) {
      const float Bv = (n < 4) ? b0[n & 3] : (n < 8) ? b1[n & 3] : (n < 12) ? b2[n & 3] : b3[n & 3];
      const float Cv = (n < 4) ? c0[n & 3] : (n < 8) ? c1[n & 3] : (n < 12) ? c2[n & 3] : c3[n & 3];
      const float dA = __expf(delta * An[n]);
      h[n] = fmaf(dA, h[n], Bv * dt);
      y = fmaf(h[n], Cv, y);
    }
    *yp = f2bf(y); yp += DI;
  }
}

// ---------------------------------------------------------------------------
extern "C" void kernel_launch(void* const* d_in, const int* in_sizes, int n_in,
                              void* d_out, int out_size, void* d_ws, size_t ws_size,
                              hipStream_t stream)
{
  const float* x      = (const float*)d_in[0];
  const float* W_in   = (const float*)d_in[1];
  const float* conv_w = (const float*)d_in[2];
  const float* conv_b = (const float*)d_in[3];
  const float* W_x    = (const float*)d_in[4];
  const float* W_dt   = (const float*)d_in[5];
  const float* b_dt   = (const float*)d_in[6];
  const float* A_log  = (const float*)d_in[7];
  const float* Dp     = (const float*)d_in[8];
  const float* W_out  = (const float*)d_in[9];
  float* out = (float*)d_out;
  char* W = (char*)d_ws;

  const size_t MB = 1u << 20;
  // byte layout -- all regions DISJOINT (ws is ~268 MB; no aliasing needed):
  u16*   XVb   = (u16*)  (W + 0);         //  8 MB (boundary rows only)
  u16*   x_bf  = (u16*)  (W + 16 * MB);   //  4 MB
  u16*   WinT  = (u16*)  (W + 20 * MB);   //  4 MB
  u16*   XSb   = (u16*)  (W + 32 * MB);   //  8 MB
  float* SSMB  = (float*)(W + 40 * MB);   //  1 MB
  u16*   WoutT = (u16*)  (W + 41 * MB);   //  4 MB
  u16*   WxT   = (u16*)  (W + 45 * MB);   // .5 MB
  float* P3    = (float*)(W + 48 * MB);   //  8 MB
  float* DELTA = (float*)(W + 56 * MB);   // 16 MB
  float* AGG_A = (float*)(W + 72 * MB);   //  8 MB
  float* AGG_H = (float*)(W + 80 * MB);   //  8 MB
  u16*   Yb    = (u16*)  (W + 88 * MB);   //  8 MB

  dim3 blk(256);

  // 0) fused preprocessing (cvt + 3 transposes + WxT pad-zero)
  prep_kernel<<<dim3(6400), blk, 0, stream>>>(
      x, W_in, W_x, W_out, x_bf, WinT, WxT, WoutT);

  // 1) xv = x @ W_in with FUSED conv+silu -> XSb (boundary xv rows -> XVb)
  mgemm<1, 64, 1, 1><<<dim3(32, 16, 1), blk, 0, stream>>>(
      x_bf, DMODEL, WinT, DMODEL, XSb, DI, DMODEL, conv_w, conv_b, XVb);

  // 2) conv fixup for tile-boundary rows ((m&127)<3)
  fixup_kernel<<<dim3(96), blk, 0, stream>>>(XVb, conv_w, conv_b, XSb);

  // 3) ssm partials (M=2048 N=128pad K=2048, TN=64 splitK=8) -> P3
  mgemm<8, 64, 0, 0><<<dim3(2, 16, 8), blk, 0, stream>>>(
      XSb, DI, WxT, DI, P3, SSMP, DI, nullptr, nullptr, nullptr);

  // 4) fused reduce(P3) + delta -> SSMB(B,C cols) + DELTA
  rd_kernel<<<dim3(512), blk, 0, stream>>>(P3, W_dt, b_dt, SSMB, DELTA);

  // 5) chunked scan (register-state)
  scan_pass1<<<dim3(BATCH * NCHUNK * (DI / 256)), blk, 0, stream>>>(
      DELTA, XSb, SSMB, A_log, AGG_A, AGG_H);
  scan_pass2<<<dim3((BATCH * DI * NSTATE) / 256), blk, 0, stream>>>(
      AGG_A, AGG_H);
  scan_pass3<<<dim3(BATCH * NCHUNK * (DI / 256)), blk, 0, stream>>>(
      DELTA, XSb, SSMB, A_log, Dp, AGG_H, Yb);

  // 6) out = y @ W_out  (M=2048 N=1024 K=2048, TN=64) -> d_out
  mgemm<1, 64, 0, 0><<<dim3(16, 16, 1), blk, 0, stream>>>(
      Yb, DI, WoutT, DI, out, DMODEL, DI, nullptr, nullptr, nullptr);
}

// Round 11
// 224.678 us; speedup vs baseline: 1.1018x; 1.0051x over previous
//
#include <hip/hip_runtime.h>
#include <math.h>

// Problem constants
#define BATCH   2
#define LSEQ    1024
#define DMODEL  1024
#define DI      2048      // D_INNER
#define NSTATE  16
#define DTR     64        // DT_RANK
#define SSMP    128       // padded ssm width (96 -> 128); B at +64, C at +80
#define MROWS   2048      // BATCH*LSEQ
#define CHUNK   32
#define NCHUNK  32        // LSEQ / CHUNK

typedef unsigned short u16;
typedef __attribute__((ext_vector_type(8))) short short8;   // 8 bf16 (4 VGPRs)
typedef __attribute__((ext_vector_type(4))) float f32x4;

__device__ __forceinline__ float silu_f(float x) {
  return x / (1.f + __expf(-x));
}
__device__ __forceinline__ float softplus_f(float x) {
  return fmaxf(x, 0.f) + __logf(1.f + __expf(-fabsf(x)));
}
__device__ __forceinline__ u16 f2bf(float f) {   // RNE
  unsigned u = __float_as_uint(f);
  return (u16)((u + 0x7fffu + ((u >> 16) & 1u)) >> 16);
}
__device__ __forceinline__ float bf2f(u16 v) {
  return __uint_as_float(((unsigned)v) << 16);
}

// async global -> LDS, 16 B per lane; LDS dest = wave-uniform base + lane*16
__device__ __forceinline__ void gload_lds16(const u16* g, u16* l) {
  __builtin_amdgcn_global_load_lds(
      (const __attribute__((address_space(1))) unsigned int*)(const void*)g,
      (__attribute__((address_space(3))) unsigned int*)(void*)l, 16, 0, 0);
}

// ---------------------------------------------------------------------------
// Fused preprocessing (one kernel, block-range dispatch).
// ---------------------------------------------------------------------------
__device__ __forceinline__ void transpose_dev(
    float (*t)[33], const float* __restrict__ in, u16* __restrict__ out,
    int R, int C, int bx, int by, int tid)
{
  const int tx = tid & 31, ty = tid >> 5;          // 32 x 8
  const int c0 = bx * 32, r0 = by * 32;
#pragma unroll
  for (int k = 0; k < 4; ++k)
    t[ty + 8 * k][tx] = in[(size_t)(r0 + ty + 8 * k) * C + c0 + tx];
  __syncthreads();
#pragma unroll
  for (int k = 0; k < 4; ++k)
    out[(size_t)(c0 + ty + 8 * k) * R + r0 + tx] = f2bf(t[tx][ty + 8 * k]);
}

__global__ __launch_bounds__(256) void prep_kernel(
    const float* __restrict__ x, const float* __restrict__ W_in,
    const float* __restrict__ W_x, const float* __restrict__ W_out,
    u16* __restrict__ x_bf, u16* __restrict__ WinT, u16* __restrict__ WxT,
    u16* __restrict__ WoutT)
{
  __shared__ float ts[32][33];
  const int tid = threadIdx.x;
  int bi = blockIdx.x;
  if (bi < 2048) {                      // cvt x
    const int i = (bi * 256 + tid) * 4;
    float4 v = *(const float4*)(x + i);
    ushort4 o;
    o.x = f2bf(v.x); o.y = f2bf(v.y); o.z = f2bf(v.z); o.w = f2bf(v.w);
    *(ushort4*)(x_bf + i) = o;
    return;
  }
  bi -= 2048;
  if (bi < 2048) {                      // W_in: grid (64, 32)
    transpose_dev(ts, W_in, WinT, 1024, 2048, bi & 63, bi >> 6, tid);
    return;
  }
  bi -= 2048;
  if (bi < 192) {                       // W_x: grid (3, 64)
    transpose_dev(ts, W_x, WxT, 2048, 96, bi % 3, bi / 3, tid);
    return;
  }
  bi -= 192;
  if (bi < 64) {                        // zero WxT rows 96..127
    const int i = (bi * 256 + tid) * 4;
    *(ushort4*)(WxT + 96 * 2048 + i) = make_ushort4(0, 0, 0, 0);
    return;
  }
  bi -= 64;
  {                                     // W_out: grid (32, 64)
    transpose_dev(ts, W_out, WoutT, 2048, 1024, bi & 31, bi >> 5, tid);
  }
}

// ---------------------------------------------------------------------------
// bf16 MFMA GEMM, m97-style: C[M x TNxgrid] = A[M x K] * Bt[N x K]^T
// Tile 128(M) x TN(N), BK=32, 256 threads = 4 waves.
// Staging: global_load_lds dwordx4 with store-side XOR chunk swizzle.
// SPLITK>1: deterministic partials at C + z*(gridDim.y*128*ldc).
// OBF==1: output bf16.
// CONV==1 (TN=64 only): wave 0 additionally computes the 16 predecessor rows
// (bm-16..bm-1) from an extra staged A-fragment, so the causal depthwise
// conv(4)+bias+SiLU epilogue covers ALL 128 rows in-tile (no fixup kernel).
// Predecessor rows are bit-identical to the neighbor block's main rows
// (same A rows x same B). Gating by global l handles sequence starts.
// ---------------------------------------------------------------------------
template<int SPLITK, int TN, int OBF, int CONV>
__global__ __launch_bounds__(256) void mgemm(
    const u16* __restrict__ A, int lda,
    const u16* __restrict__ Bt, int ldb,
    void* __restrict__ Cv, int ldc, int K,
    const float* __restrict__ cw, const float* __restrict__ cb)
{
  constexpr int WI = (TN == 128) ? 4 : 2;   // a-frags per wave
  __shared__ u16 Al[128 * 32];
  __shared__ u16 Bl[TN * 32];
  const int tid = threadIdx.x;
  const int bm = blockIdx.y * 128;
  const int bn = blockIdx.x * TN;
  const int lane = tid & 63;
  const int w = tid >> 6;
  const int wm = (TN == 128) ? (w & 1) * 64 : w * 32;
  const int wn = (TN == 128) ? (w >> 1) * 64 : 0;
  const int quad = lane >> 4;
  const int lm = lane & 15;

  const int Kper = K / SPLITK;
  const int k_beg = blockIdx.z * Kper;

  const int clog8 = (((lane & 3) ^ ((lane >> 3) & 3)) << 3);  // u16 offset
  const int rA = w * 32 + (lane >> 2);
  const int rB = ((TN == 128) ? w * 32 : w * 16) + (lane >> 2);
  const u16* gA0 = A + (size_t)(bm + rA) * lda + k_beg + clog8;
  const u16* gA1 = gA0 + (size_t)16 * lda;
  const u16* gB0 = Bt + (size_t)(bn + rB) * ldb + k_beg + clog8;
  const u16* gB1 = gB0 + (size_t)16 * ldb;
  u16* lA0 = &Al[(w * 32) * 32];
  u16* lA1 = &Al[(w * 32 + 16) * 32];
  u16* lB0 = &Bl[(((TN == 128) ? w * 32 : w * 16)) * 32];
  u16* lB1 = &Bl[((TN == 128) ? (w * 32 + 16) : 0) * 32];

  const int cph8 = ((quad ^ ((lm >> 1) & 3)) << 3);

  // CONV extension: predecessor-row A fragment (wave 0 only)
  __shared__ u16 Aext[CONV ? 16 * 32 : 1];
  const u16* gAE = nullptr;
  if constexpr (CONV) {
    int er = bm - 16 + (lane >> 2);
    if (er < 0) er = 0;                 // bm==0: values gated off by l-checks
    gAE = A + (size_t)er * lda + k_beg + clog8;
  }

  f32x4 acc[WI][4] = {};
  f32x4 accE[CONV ? 4 : 1] = {};

  for (int ks = 0; ks < Kper; ks += 32) {
    gload_lds16(gA0, lA0);
    gload_lds16(gA1, lA1);
    gload_lds16(gB0, lB0);
    if (TN == 128) gload_lds16(gB1, lB1);
    if constexpr (CONV) {
      if (w == 0) gload_lds16(gAE, Aext);
      gAE += 32;
    }
    gA0 += 32; gA1 += 32; gB0 += 32; gB1 += 32;
    __syncthreads();

    short8 a[WI], b[4];
#pragma unroll
    for (int i = 0; i < WI; ++i)
      a[i] = *(const short8*)&Al[(wm + i * 16 + lm) * 32 + cph8];
#pragma unroll
    for (int j = 0; j < 4; ++j)
      b[j] = *(const short8*)&Bl[(wn + j * 16 + lm) * 32 + cph8];
#pragma unroll
    for (int i = 0; i < WI; ++i)
#pragma unroll
      for (int j = 0; j < 4; ++j)
        acc[i][j] = __builtin_amdgcn_mfma_f32_16x16x32_bf16(a[i], b[j], acc[i][j], 0, 0, 0);
    if constexpr (CONV) {
      if (w == 0) {
        const short8 aE = *(const short8*)&Aext[lm * 32 + cph8];
#pragma unroll
        for (int j = 0; j < 4; ++j)
          accE[j] = __builtin_amdgcn_mfma_f32_16x16x32_bf16(aE, b[j], accE[j], 0, 0, 0);
      }
    }
    __syncthreads();
  }

  if constexpr (CONV) {
    // ---- fused conv epilogue (TN==64), 144-row xv tile in LDS ----
    __shared__ u16 xvs[144 * 68];   // row stride 68 u16 (8B-aligned rows)
    if (w == 0) {
#pragma unroll
      for (int r = 0; r < 4; ++r)
#pragma unroll
        for (int j = 0; j < 4; ++j)
          xvs[(quad * 4 + r) * 68 + j * 16 + lm] = f2bf(accE[j][r]);
    }
#pragma unroll
    for (int i = 0; i < WI; ++i)
#pragma unroll
      for (int r = 0; r < 4; ++r)
#pragma unroll
        for (int j = 0; j < 4; ++j)
          xvs[(16 + wm + i * 16 + quad * 4 + r) * 68 + j * 16 + lm] =
              f2bf(acc[i][j][r]);
    __syncthreads();

    const int rblk = tid >> 4;          // 0..15 -> 8 rows each
    const int c4 = (tid & 15) * 4;      // 0..60
    const int dg = bn + c4;
    float cwv[4][4], cbv[4];
#pragma unroll
    for (int cc = 0; cc < 4; ++cc) {
      const float4 wv = *(const float4*)&cw[(size_t)(dg + cc) * 4];
      cwv[cc][0] = wv.x; cwv[cc][1] = wv.y; cwv[cc][2] = wv.z; cwv[cc][3] = wv.w;
      cbv[cc] = cb[dg + cc];
    }
    float a3[4], a2[4], a1[4], a0[4];
    auto ldrow = [&](int xr, float* o) {
      const ushort4 u = *(const ushort4*)&xvs[xr * 68 + c4];
      o[0] = bf2f(u.x); o[1] = bf2f(u.y); o[2] = bf2f(u.z); o[3] = bf2f(u.w);
    };
    ldrow(16 + rblk * 8 - 3, a3);
    ldrow(16 + rblk * 8 - 2, a2);
    ldrow(16 + rblk * 8 - 1, a1);
    u16* XSb = (u16*)Cv;
#pragma unroll
    for (int rr = 0; rr < 8; ++rr) {
      const int lr = rblk * 8 + rr;
      const int m = bm + lr;
      const int l = m & (LSEQ - 1);
      ldrow(16 + lr, a0);
      ushort4 o;
      u16* oe = (u16*)&o;
#pragma unroll
      for (int cc = 0; cc < 4; ++cc) {
        float s = cbv[cc];
        s = fmaf(cwv[cc][3], a0[cc], s);
        if (l >= 1) s = fmaf(cwv[cc][2], a1[cc], s);
        if (l >= 2) s = fmaf(cwv[cc][1], a2[cc], s);
        if (l >= 3) s = fmaf(cwv[cc][0], a3[cc], s);
        oe[cc] = f2bf(silu_f(s));
      }
      *(ushort4*)&XSb[(size_t)m * ldc + dg] = o;
#pragma unroll
      for (int cc = 0; cc < 4; ++cc) { a3[cc] = a2[cc]; a2[cc] = a1[cc]; a1[cc] = a0[cc]; }
    }
  } else {
#pragma unroll
    for (int i = 0; i < WI; ++i) {
#pragma unroll
      for (int r = 0; r < 4; ++r) {
        const int row = bm + wm + i * 16 + quad * 4 + r;
#pragma unroll
        for (int j = 0; j < 4; ++j) {
          const int col = bn + wn + j * 16 + lm;
          float v = acc[i][j][r];
          if (OBF) {
            ((u16*)Cv)[(size_t)row * ldc + col] = f2bf(v);
          } else {
            float* Cz = (float*)Cv;
            if (SPLITK > 1) Cz += (size_t)blockIdx.z * gridDim.y * 128 * ldc;
            Cz[(size_t)row * ldc + col] = v;
          }
        }
      }
    }
  }
}

// ---------------------------------------------------------------------------
// Fused reduce(P3 splitK=8) + delta. Grid 512: (row-group of 8) x (col half).
// Half-0 blocks also emit SSMB's B/C columns (64..95).
// ---------------------------------------------------------------------------
__global__ __launch_bounds__(256) void rd_kernel(
    const float* __restrict__ P3, const float* __restrict__ W_dt,
    const float* __restrict__ b_dt, float* __restrict__ SSMB,
    float* __restrict__ DELTA)
{
  __shared__ float dts[8][64];
  const int tid = threadIdx.x;
  const int r0 = (blockIdx.x >> 1) * 8;
  const int half = blockIdx.x & 1;
  {
    const int i = tid * 2;
    const int r = i >> 6, k = i & 63;
    float sx = 0.f, sy = 0.f;
#pragma unroll
    for (int z = 0; z < 8; ++z) {
      const float2 v = *(const float2*)&P3[(size_t)z * (MROWS * SSMP) +
                                           (size_t)(r0 + r) * SSMP + k];
      sx += v.x; sy += v.y;
    }
    dts[r][k] = sx; dts[r][k + 1] = sy;
  }
  if (half == 0) {
    const int r = tid >> 5, c = DTR + (tid & 31);
    float s = 0.f;
#pragma unroll
    for (int z = 0; z < 8; ++z)
      s += P3[(size_t)z * (MROWS * SSMP) + (size_t)(r0 + r) * SSMP + c];
    SSMB[(size_t)(r0 + r) * SSMP + c] = s;
  }
  __syncthreads();

  const int c0 = half * 1024 + tid * 4;
  float acc[8][4];
  {
    const float4 bv = *(const float4*)&b_dt[c0];
#pragma unroll
    for (int r = 0; r < 8; ++r) {
      acc[r][0] = bv.x; acc[r][1] = bv.y; acc[r][2] = bv.z; acc[r][3] = bv.w;
    }
  }
#pragma unroll 4
  for (int k = 0; k < DTR; ++k) {
    const float4 w = *(const float4*)&W_dt[(size_t)k * DI + c0];
#pragma unroll
    for (int r = 0; r < 8; ++r) {
      const float d = dts[r][k];
      acc[r][0] = fmaf(w.x, d, acc[r][0]);
      acc[r][1] = fmaf(w.y, d, acc[r][1]);
      acc[r][2] = fmaf(w.z, d, acc[r][2]);
      acc[r][3] = fmaf(w.w, d, acc[r][3]);
    }
  }
#pragma unroll
  for (int r = 0; r < 8; ++r) {
    float4 o;
    o.x = softplus_f(acc[r][0]); o.y = softplus_f(acc[r][1]);
    o.z = softplus_f(acc[r][2]); o.w = softplus_f(acc[r][3]);
    *(float4*)&DELTA[(size_t)(r0 + r) * DI + c0] = o;
  }
}

// ---------------------------------------------------------------------------
// Chunked parallel scan, register-state version (one thread per (b,chunk,d)).
// ---------------------------------------------------------------------------
__global__ __launch_bounds__(256) void scan_pass1(
    const float* __restrict__ DELTA, const u16* __restrict__ XSb,
    const float* __restrict__ SSMB, const float* __restrict__ A_log,
    float* __restrict__ AGG_A, float* __restrict__ AGG_H)
{
  __shared__ float Bs[CHUNK * 16];
  const int tid = threadIdx.x;
  const int db = blockIdx.x & 7;
  const int c  = (blockIdx.x >> 3) & (NCHUNK - 1);
  const int b  = blockIdx.x >> 8;
  const int d  = db * 256 + tid;
  const int l0 = c * CHUNK;

  for (int i = tid; i < CHUNK * 16; i += 256) {
    const int l = i >> 4, n = i & 15;
    Bs[i] = SSMB[((size_t)(b * LSEQ + l0 + l)) * SSMP + DTR + n];
  }
  __syncthreads();

  float An[16];
  {
    const float* ar = A_log + d * 16;
#pragma unroll
    for (int n = 0; n < 16; ++n) An[n] = -__expf(ar[n]);
  }

  float h[16];
#pragma unroll
  for (int n = 0; n < 16; ++n) h[n] = 0.f;
  float S = 0.f;

  const float* dp = DELTA + ((size_t)(b * LSEQ + l0)) * DI + d;
  const u16*   xp = XSb   + ((size_t)(b * LSEQ + l0)) * DI + d;

  for (int l = 0; l < CHUNK; ++l) {
    const float delta = *dp; dp += DI;
    const float xv = bf2f(*xp); xp += DI;
    S += delta;
    const float dt = delta * xv;
    const f32x4 b0 = *(const f32x4*)&Bs[l * 16];
    const f32x4 b1 = *(const f32x4*)&Bs[l * 16 + 4];
    const f32x4 b2 = *(const f32x4*)&Bs[l * 16 + 8];
    const f32x4 b3 = *(const f32x4*)&Bs[l * 16 + 12];
#pragma unroll
    for (int n = 0; n < 16; ++n) {
      const float Bv = (n < 4) ? b0[n & 3] : (n < 8) ? b1[n & 3] : (n < 12) ? b2[n & 3] : b3[n & 3];
      const float dA = __expf(delta * An[n]);
      h[n] = fmaf(dA, h[n], Bv * dt);
    }
  }

  const size_t base = (((size_t)(b * NCHUNK + c) * DI + d) << 4);
  f32x4 oa[4], oh[4];
#pragma unroll
  for (int q = 0; q < 4; ++q) {
#pragma unroll
    for (int r = 0; r < 4; ++r) {
      oa[q][r] = __expf(An[q * 4 + r] * S);
      oh[q][r] = h[q * 4 + r];
    }
    *(f32x4*)&AGG_A[base + q * 4] = oa[q];
    *(f32x4*)&AGG_H[base + q * 4] = oh[q];
  }
}

// In-place prefix over chunks: AGG_H[ai] <- exclusive prefix (h_init).
__global__ __launch_bounds__(256) void scan_pass2(
    const float* __restrict__ AGG_A, float* __restrict__ AGG_H)
{
  const int t = blockIdx.x * 256 + threadIdx.x;   // over B*DI*NSTATE
  const int dn = t & (DI * NSTATE - 1);
  const int b = t >> 15;
  size_t ai = (size_t)b * NCHUNK * DI * NSTATE + dn;
  const size_t stride = (size_t)DI * NSTATE;
  float h = 0.f;
#pragma unroll
  for (int c = 0; c < NCHUNK; ++c) {
    const float a = AGG_A[ai];
    const float hp = AGG_H[ai];
    AGG_H[ai] = h;
    h = fmaf(a, h, hp);
    ai += stride;
  }
}

__global__ __launch_bounds__(256) void scan_pass3(
    const float* __restrict__ DELTA, const u16* __restrict__ XSb,
    const float* __restrict__ SSMB, const float* __restrict__ A_log,
    const float* __restrict__ Dp, const float* __restrict__ HINIT,
    u16* __restrict__ Yb)
{
  __shared__ float Bs[CHUNK * 16];
  __shared__ float Cs[CHUNK * 16];
  const int tid = threadIdx.x;
  const int db = blockIdx.x & 7;
  const int c  = (blockIdx.x >> 3) & (NCHUNK - 1);
  const int b  = blockIdx.x >> 8;
  const int d  = db * 256 + tid;
  const int l0 = c * CHUNK;

  for (int i = tid; i < CHUNK * 16; i += 256) {
    const int l = i >> 4, n = i & 15;
    const size_t row = ((size_t)(b * LSEQ + l0 + l)) * SSMP;
    Bs[i] = SSMB[row + DTR + n];
    Cs[i] = SSMB[row + DTR + NSTATE + n];
  }
  __syncthreads();

  float An[16];
  {
    const float* ar = A_log + d * 16;
#pragma unroll
    for (int n = 0; n < 16; ++n) An[n] = -__expf(ar[n]);
  }
  const float Dd = Dp[d];

  const size_t base = (((size_t)(b * NCHUNK + c) * DI + d) << 4);
  float h[16];
#pragma unroll
  for (int q = 0; q < 4; ++q) {
    const f32x4 hv = *(const f32x4*)&HINIT[base + q * 4];
#pragma unroll
    for (int r = 0; r < 4; ++r) h[q * 4 + r] = hv[r];
  }

  const float* dp = DELTA + ((size_t)(b * LSEQ + l0)) * DI + d;
  const u16*   xp = XSb   + ((size_t)(b * LSEQ + l0)) * DI + d;
  u16*         yp = Yb    + ((size_t)(b * LSEQ + l0)) * DI + d;

  for (int l = 0; l < CHUNK; ++l) {
    const float delta = *dp; dp += DI;
    const float xv = bf2f(*xp); xp += DI;
    const float dt = delta * xv;
    float y = xv * Dd;
    const f32x4 b0 = *(const f32x4*)&Bs[l * 16];
    const f32x4 b1 = *(const f32x4*)&Bs[l * 16 + 4];
    const f32x4 b2 = *(const f32x4*)&Bs[l * 16 + 8];
    const f32x4 b3 = *(const f32x4*)&Bs[l * 16 + 12];
    const f32x4 c0 = *(const f32x4*)&Cs[l * 16];
    const f32x4 c1 = *(const f32x4*)&Cs[l * 16 + 4];
    const f32x4 c2 = *(const f32x4*)&Cs[l * 16 + 8];
    const f32x4 c3 = *(const f32x4*)&Cs[l * 16 + 12];
#pragma unroll
    for (int n = 0; n < 16; ++n) {
      const float Bv = (n < 4) ? b0[n & 3] : (n < 8) ? b1[n & 3] : (n < 12) ? b2[n & 3] : b3[n & 3];
      const float Cv = (n < 4) ? c0[n & 3] : (n < 8) ? c1[n & 3] : (n < 12) ? c2[n & 3] : c3[n & 3];
      const float dA = __expf(delta * An[n]);
      h[n] = fmaf(dA, h[n], Bv * dt);
      y = fmaf(h[n], Cv, y);
    }
    *yp = f2bf(y); yp += DI;
  }
}

// ---------------------------------------------------------------------------
extern "C" void kernel_launch(void* const* d_in, const int* in_sizes, int n_in,
                              void* d_out, int out_size, void* d_ws, size_t ws_size,
                              hipStream_t stream)
{
  const float* x      = (const float*)d_in[0];
  const float* W_in   = (const float*)d_in[1];
  const float* conv_w = (const float*)d_in[2];
  const float* conv_b = (const float*)d_in[3];
  const float* W_x    = (const float*)d_in[4];
  const float* W_dt   = (const float*)d_in[5];
  const float* b_dt   = (const float*)d_in[6];
  const float* A_log  = (const float*)d_in[7];
  const float* Dp     = (const float*)d_in[8];
  const float* W_out  = (const float*)d_in[9];
  float* out = (float*)d_out;
  char* W = (char*)d_ws;

  const size_t MB = 1u << 20;
  // byte layout -- all regions disjoint:
  u16*   x_bf  = (u16*)  (W + 16 * MB);   //  4 MB
  u16*   WinT  = (u16*)  (W + 20 * MB);   //  4 MB
  u16*   XSb   = (u16*)  (W + 32 * MB);   //  8 MB
  float* SSMB  = (float*)(W + 40 * MB);   //  1 MB
  u16*   WoutT = (u16*)  (W + 41 * MB);   //  4 MB
  u16*   WxT   = (u16*)  (W + 45 * MB);   // .5 MB
  float* P3    = (float*)(W + 48 * MB);   //  8 MB
  float* DELTA = (float*)(W + 56 * MB);   // 16 MB
  float* AGG_A = (float*)(W + 72 * MB);   //  8 MB
  float* AGG_H = (float*)(W + 80 * MB);   //  8 MB
  u16*   Yb    = (u16*)  (W + 88 * MB);   //  8 MB

  dim3 blk(256);

  // 0) fused preprocessing (cvt + 3 transposes + WxT pad-zero)
  prep_kernel<<<dim3(6400), blk, 0, stream>>>(
      x, W_in, W_x, W_out, x_bf, WinT, WxT, WoutT);

  // 1) xv = x @ W_in with FULLY fused conv+silu (incl. boundary rows) -> XSb
  mgemm<1, 64, 1, 1><<<dim3(32, 16, 1), blk, 0, stream>>>(
      x_bf, DMODEL, WinT, DMODEL, XSb, DI, DMODEL, conv_w, conv_b);

  // 2) ssm partials (M=2048 N=128pad K=2048, TN=64 splitK=8) -> P3
  mgemm<8, 64, 0, 0><<<dim3(2, 16, 8), blk, 0, stream>>>(
      XSb, DI, WxT, DI, P3, SSMP, DI, nullptr, nullptr);

  // 3) fused reduce(P3) + delta -> SSMB(B,C cols) + DELTA
  rd_kernel<<<dim3(512), blk, 0, stream>>>(P3, W_dt, b_dt, SSMB, DELTA);

  // 4) chunked scan (register-state)
  scan_pass1<<<dim3(BATCH * NCHUNK * (DI / 256)), blk, 0, stream>>>(
      DELTA, XSb, SSMB, A_log, AGG_A, AGG_H);
  scan_pass2<<<dim3((BATCH * DI * NSTATE) / 256), blk, 0, stream>>>(
      AGG_A, AGG_H);
  scan_pass3<<<dim3(BATCH * NCHUNK * (DI / 256)), blk, 0, stream>>>(
      DELTA, XSb, SSMB, A_log, Dp, AGG_H, Yb);

  // 5) out = y @ W_out  (M=2048 N=1024 K=2048, TN=64) -> d_out
  mgemm<1, 64, 0, 0><<<dim3(16, 16, 1), blk, 0, stream>>>(
      Yb, DI, WoutT, DI, out, DMODEL, DI, nullptr, nullptr);
}